// Round 2
// baseline (1617.149 us; speedup 1.0000x reference)
//
#include <hip/hip_runtime.h>
#include <hip/hip_bf16.h>
#include <math.h>

// Problem: SurMoE. B=32, N1=512, N2=256, D=256, H=8, HD=32, S=768.
// Outputs: gene (32,512,256) f32 then img (32,256,256) f32, concat flat.
#define B_ 32
#define N1_ 512
#define N2_ 256
#define D_ 256
#define S_ 768
#define IMG_OFF 4194304  // 32*512*256

// ---------------- means (deterministic partial sums) ----------------
// mp[(b*8+s)*512 + {d | 256+d}] = partial means over 1/8 of rows
__global__ void k_mean(const float* __restrict__ x1, const float* __restrict__ x2,
                       float* __restrict__ mp) {
  int b = blockIdx.x >> 3;
  int s = blockIdx.x & 7;
  int d = threadIdx.x;
  float s1 = 0.f;
  const float* p1 = x1 + ((size_t)(b*N1_ + s*64))*D_ + d;
  for (int n = 0; n < 64; ++n) s1 += p1[(size_t)n*D_];
  float s2 = 0.f;
  const float* p2 = x2 + ((size_t)(b*N2_ + s*32))*D_ + d;
  for (int n = 0; n < 32; ++n) s2 += p2[(size_t)n*D_];
  mp[(size_t)(b*8+s)*512 + d]       = s1 * (1.0f/512.0f);
  mp[(size_t)(b*8+s)*512 + 256 + d] = s2 * (1.0f/256.0f);
}

// ---------------- router head: h = gelu(LN(m@r_w1^T+b)), w = softmax(h@r_w2^T+b) ----------------
__global__ void k_head(const float* __restrict__ mp, const float* __restrict__ r_w1,
                       const float* __restrict__ r_b1, const float* __restrict__ ln_g,
                       const float* __restrict__ ln_b, const float* __restrict__ r_w2,
                       const float* __restrict__ r_b2, float* __restrict__ wout) {
  int b = blockIdx.x;
  int j = threadIdx.x;  // 256
  __shared__ float ms[512];
  __shared__ float red[256];
  float a0 = 0.f, a1 = 0.f;
  for (int s = 0; s < 8; ++s) {         // fixed order -> deterministic
    a0 += mp[(size_t)(b*8+s)*512 + j];
    a1 += mp[(size_t)(b*8+s)*512 + 256 + j];
  }
  ms[j] = a0; ms[j+256] = a1;
  __syncthreads();
  float acc = r_b1[j];
  const float* wrow = r_w1 + (size_t)j*512;
  for (int k = 0; k < 512; ++k) acc += ms[k]*wrow[k];
  red[j] = acc; __syncthreads();
  for (int off=128; off>0; off>>=1){ if (j<off) red[j]+=red[j+off]; __syncthreads(); }
  float mu = red[0] * (1.f/256.f); __syncthreads();
  float cd = acc - mu;
  red[j] = cd*cd; __syncthreads();
  for (int off=128; off>0; off>>=1){ if (j<off) red[j]+=red[j+off]; __syncthreads(); }
  float var = red[0]*(1.f/256.f); __syncthreads();
  float xn = cd * rsqrtf(var + 1e-5f) * ln_g[j] + ln_b[j];
  float h = 0.5f*xn*(1.f+erff(xn*0.70710678118654752f));  // exact gelu
  float lg[4];
  for (int e=0;e<4;++e){
    red[j] = h * r_w2[e*256 + j]; __syncthreads();
    for (int off=128; off>0; off>>=1){ if (j<off) red[j]+=red[j+off]; __syncthreads(); }
    lg[e] = red[0] + r_b2[e]; __syncthreads();
  }
  if (j==0){
    float mx = fmaxf(fmaxf(lg[0],lg[1]),fmaxf(lg[2],lg[3]));
    float e0=expf(lg[0]-mx),e1=expf(lg[1]-mx),e2=expf(lg[2]-mx),e3=expf(lg[3]-mx);
    float s=e0+e1+e2+e3;
    wout[b*4+0]=e0/s; wout[b*4+1]=e1/s; wout[b*4+2]=e2/s; wout[b*4+3]=e3/s;
  }
}

__device__ __forceinline__ float eluf(float v) { return v > 0.f ? v : expm1f(v); }

// ---------------- lf path: out = w0*elu(z@lf_w^T + lf_b) + w3*z (covers ALL outputs) ----------------
__global__ void k_lf(const float* __restrict__ x1, const float* __restrict__ x2,
                     const float* __restrict__ lf_w, const float* __restrict__ lf_b,
                     const float* __restrict__ wgt, float* __restrict__ out) {
  int dt = blockIdx.x, nt = blockIdx.y, b = blockIdx.z;
  int tid = threadIdx.x;
  __shared__ float As[64][33];
  __shared__ float Ws[64][33];
  float acc[4][4] = {};
  int r0 = (tid >> 4) * 4;
  int c0 = (tid & 15) * 4;
  int n0 = nt*64, d0 = dt*64;
  for (int k0 = 0; k0 < 256; k0 += 32) {
    for (int i = 0; i < 8; ++i) {
      int l = tid + i*256;
      int r = l >> 5, kk = l & 31;
      int n = n0 + r;
      const float* src = (n < N1_) ? (x1 + ((size_t)(b*N1_ + n))*D_)
                                   : (x2 + ((size_t)(b*N2_ + (n-N1_)))*D_);
      As[r][kk] = src[k0+kk];
      Ws[r][kk] = lf_w[(size_t)(d0 + r)*D_ + k0 + kk];
    }
    __syncthreads();
    for (int kk = 0; kk < 32; ++kk) {
      float a[4], w[4];
      for (int i=0;i<4;++i) a[i]=As[r0+i][kk];
      for (int j=0;j<4;++j) w[j]=Ws[c0+j][kk];
      for (int i=0;i<4;++i) for (int j=0;j<4;++j) acc[i][j] += a[i]*w[j];
    }
    __syncthreads();
  }
  float w0 = wgt[b*4+0], w3 = wgt[b*4+3];
  for (int i=0;i<4;++i){
    int n = n0 + r0 + i;
    const float* zrow = (n<N1_)? (x1 + ((size_t)(b*N1_+n))*D_) : (x2 + ((size_t)(b*N2_+(n-N1_)))*D_);
    float* orow = (n<N1_)? (out + ((size_t)(b*N1_+n))*D_)
                         : (out + (size_t)IMG_OFF + ((size_t)(b*N2_+(n-N1_)))*D_);
    for (int j=0;j<4;++j){
      int d = d0 + c0 + j;
      float v = acc[i][j] + lf_b[d];
      orow[d] = w0*eluf(v) + w3*zrow[d];
    }
  }
}

// ---------------- x_out path: a1 = elu(x1@af2^T+b2), a2 = elu(af3@x2[b]+b3[n]); out += w1*(a1+a2) ----------------
__global__ void k_xout(const float* __restrict__ x1, const float* __restrict__ x2,
                       const float* __restrict__ af2_w, const float* __restrict__ af2_b,
                       const float* __restrict__ af3_w, const float* __restrict__ af3_b,
                       const float* __restrict__ wgt, float* __restrict__ out) {
  int dt = blockIdx.x, nt = blockIdx.y, b = blockIdx.z;
  int tid = threadIdx.x;
  __shared__ float As1[64][33];  // x1 rows (n,k)
  __shared__ float Ws1[64][33];  // af2_w rows (d,k)
  __shared__ float As2[64][33];  // af3_w rows (n,k2)
  __shared__ float Bs2[32][65];  // x2[b] (k2,d)
  float acc1[4][4] = {}, acc2[4][4] = {};
  int r0 = (tid>>4)*4, c0 = (tid&15)*4;
  int n0 = nt*64, d0 = dt*64;
  for (int k0=0;k0<256;k0+=32){
    for (int i=0;i<8;++i){
      int l = tid + i*256; int r = l>>5, kk = l&31;
      As1[r][kk] = x1[((size_t)(b*N1_ + n0 + r))*D_ + k0+kk];
      Ws1[r][kk] = af2_w[(size_t)(d0+r)*D_ + k0+kk];
      As2[r][kk] = af3_w[(size_t)(n0+r)*D_ + k0+kk];
    }
    for (int i=0;i<8;++i){
      int l = tid + i*256; int r = l>>6, cc = l&63;
      Bs2[r][cc] = x2[((size_t)(b*N2_ + k0 + r))*D_ + d0 + cc];
    }
    __syncthreads();
    for (int kk=0; kk<32; ++kk){
      float a1[4], w1_[4], a2[4], b2[4];
      for (int i=0;i<4;++i){ a1[i]=As1[r0+i][kk]; a2[i]=As2[r0+i][kk]; }
      for (int j=0;j<4;++j){ w1_[j]=Ws1[c0+j][kk]; b2[j]=Bs2[kk][c0+j]; }
      for (int i=0;i<4;++i) for (int j=0;j<4;++j){ acc1[i][j]+=a1[i]*w1_[j]; acc2[i][j]+=a2[i]*b2[j]; }
    }
    __syncthreads();
  }
  float w1v = wgt[b*4+1];
  for (int i=0;i<4;++i){
    int n = n0+r0+i;
    float* grow = out + ((size_t)(b*N1_+n))*D_;
    float* irow = (n<N2_)? (out + (size_t)IMG_OFF + ((size_t)(b*N2_+n))*D_) : nullptr;
    for (int j=0;j<4;++j){
      int d = d0+c0+j;
      float xo = eluf(acc1[i][j] + af2_b[d]) + eluf(acc2[i][j] + af3_b[n]);
      grow[d] += w1v*xo;
      if (irow) irow[d] += w1v*xo;
    }
  }
}

// ---------------- kv = z @ attn_in_w[256:768]^T + b -> bf16 ws ----------------
// layout: kv[((b*S + n)*512) + c], c in [0,256) = k (head h -> c=h*32+d), [256,512) = v
__global__ void k_kv(const float* __restrict__ x1, const float* __restrict__ x2,
                     const float* __restrict__ w, const float* __restrict__ bias,
                     __hip_bfloat16* __restrict__ kv) {
  int ct = blockIdx.x, nt = blockIdx.y, b = blockIdx.z;
  int tid = threadIdx.x;
  __shared__ float As[64][33];
  __shared__ float Ws[64][33];
  float acc[4][4] = {};
  int r0 = (tid>>4)*4, c0 = (tid&15)*4;
  int n0 = nt*64, cc0 = ct*64;
  for (int k0=0;k0<256;k0+=32){
    for (int i=0;i<8;++i){
      int l = tid + i*256; int r = l>>5, kk = l&31;
      int n = n0 + r;
      const float* src = (n < N1_) ? (x1 + ((size_t)(b*N1_ + n))*D_)
                                   : (x2 + ((size_t)(b*N2_ + (n-N1_)))*D_);
      As[r][kk] = src[k0+kk];
      Ws[r][kk] = w[(size_t)(256 + cc0 + r)*D_ + k0 + kk];  // weight rows 256..767
    }
    __syncthreads();
    for (int kk=0; kk<32; ++kk){
      float a[4], wv[4];
      for (int i=0;i<4;++i) a[i]=As[r0+i][kk];
      for (int j=0;j<4;++j) wv[j]=Ws[c0+j][kk];
      for (int i=0;i<4;++i) for (int j=0;j<4;++j) acc[i][j] += a[i]*wv[j];
    }
    __syncthreads();
  }
  for (int i=0;i<4;++i){
    int n = n0+r0+i;
    __hip_bfloat16* row = kv + ((size_t)b*S_ + n)*512;
    for (int j=0;j<4;++j){
      int c = cc0+c0+j;
      row[c] = __float2bfloat16(acc[i][j] + bias[256 + c]);
    }
  }
}

// ---------------- flash attention per (b,h,qtile=64), q computed on the fly ----------------
__global__ void k_attn(const float* __restrict__ x1, const float* __restrict__ x2,
                       const float* __restrict__ attn_in_w, const float* __restrict__ attn_in_b,
                       const __hip_bfloat16* __restrict__ kv,
                       __hip_bfloat16* __restrict__ obuf) {
  int qt = blockIdx.x, h = blockIdx.y, b = blockIdx.z;
  int tid = threadIdx.x;
  int r = tid >> 2;   // q-row in tile 0..63
  int c4 = tid & 3;   // column group
  __shared__ float Qs[64][33];
  __shared__ float Ks[64][33];
  __shared__ float Vs[64][33];
  __shared__ float Ps[64][68];

  // --- stage 1: Qs = z_tile @ Wq_h^T + bias (reuse Ks as z-chunk, Vs as w-chunk) ---
  float qacc[8] = {};
  for (int k0 = 0; k0 < 256; k0 += 32) {
    for (int i=0;i<8;++i){
      int l = tid + i*256; int rr = l>>5, kk = l&31;
      int n = qt*64 + rr;
      const float* src = (n < N1_) ? (x1 + ((size_t)(b*N1_ + n))*D_)
                                   : (x2 + ((size_t)(b*N2_ + (n-N1_)))*D_);
      Ks[rr][kk] = src[k0+kk];
    }
    for (int i=0;i<4;++i){
      int l = tid + i*256; int rr = l>>5, kk = l&31;  // rr<32
      Vs[rr][kk] = attn_in_w[(size_t)(h*32 + rr)*D_ + k0 + kk];
    }
    __syncthreads();
    for (int kk=0; kk<32; ++kk){
      float a = Ks[r][kk];
      for (int jj=0;jj<8;++jj) qacc[jj] += a * Vs[c4*8+jj][kk];
    }
    __syncthreads();
  }
  for (int jj=0;jj<8;++jj) Qs[r][c4*8+jj] = qacc[jj] + attn_in_b[h*32 + c4*8 + jj];
  // Qs consumed after the barrier at top of the kt loop.

  // --- stage 2: flash over kv ---
  float m_i = -INFINITY, l_i = 0.f;
  float o[8] = {};
  const float scale = 0.17677669529663689f; // 1/sqrt(32)
  const __hip_bfloat16* kvb = kv + (size_t)b*S_*512;
  for (int kt=0; kt<12; ++kt){
    __syncthreads();
    for (int i=0;i<8;++i){
      int l = tid + i*256; int rr = l>>5, kk = l&31;
      const __hip_bfloat16* kr = kvb + (size_t)(kt*64+rr)*512 + h*32 + kk;
      Ks[rr][kk] = __bfloat162float(kr[0]);
      Vs[rr][kk] = __bfloat162float(kr[256]);
    }
    __syncthreads();
    float s[16];
    for (int j=0;j<16;++j){
      int col = c4*16+j;
      float acc = 0.f;
      for (int kk=0;kk<32;++kk) acc += Qs[r][kk]*Ks[col][kk];
      s[j] = acc*scale;
    }
    float mloc = s[0];
    for (int j=1;j<16;++j) mloc = fmaxf(mloc, s[j]);
    mloc = fmaxf(mloc, __shfl_xor(mloc, 1, 64));
    mloc = fmaxf(mloc, __shfl_xor(mloc, 2, 64));
    float m_new = fmaxf(m_i, mloc);
    float alpha = expf(m_i - m_new);  // exp(-inf)=0 on first tile
    float lloc = 0.f;
    for (int j=0;j<16;++j){ float p = expf(s[j]-m_new); Ps[r][c4*16+j] = p; lloc += p; }
    lloc += __shfl_xor(lloc, 1, 64);
    lloc += __shfl_xor(lloc, 2, 64);
    l_i = l_i*alpha + lloc;
    m_i = m_new;
    for (int jj=0;jj<8;++jj) o[jj] *= alpha;
    // Ps row r written+read by the same 4 lanes of one wave -> no barrier needed
    for (int c=0;c<64;++c){
      float p = Ps[r][c];
      for (int jj=0;jj<8;++jj) o[jj] += p * Vs[c][c4*8+jj];
    }
  }
  float inv = 1.f/l_i;
  int n = qt*64 + r;
  __hip_bfloat16* orow = obuf + ((size_t)b*S_ + n)*D_ + h*32 + c4*8;
  for (int jj=0;jj<8;++jj) orow[jj] = __float2bfloat16(o[jj]*inv);
}

// ---------------- out-projection: out += w2*(o @ attn_out_w^T + attn_out_b) ----------------
__global__ void k_proj(const __hip_bfloat16* __restrict__ obuf, const float* __restrict__ w,
                       const float* __restrict__ bias, const float* __restrict__ wgt,
                       float* __restrict__ out) {
  int dt = blockIdx.x, nt = blockIdx.y, b = blockIdx.z;
  int tid = threadIdx.x;
  __shared__ float As[64][33];
  __shared__ float Ws[64][33];
  float acc[4][4] = {};
  int r0 = (tid>>4)*4, c0 = (tid&15)*4;
  int n0 = nt*64, d0 = dt*64;
  for (int k0=0;k0<256;k0+=32){
    for (int i=0;i<8;++i){
      int l = tid + i*256; int r = l>>5, kk = l&31;
      As[r][kk] = __bfloat162float(obuf[((size_t)b*S_ + n0 + r)*D_ + k0+kk]);
      Ws[r][kk] = w[(size_t)(d0+r)*D_ + k0+kk];
    }
    __syncthreads();
    for (int kk=0; kk<32; ++kk){
      float a[4], wv[4];
      for (int i=0;i<4;++i) a[i]=As[r0+i][kk];
      for (int j=0;j<4;++j) wv[j]=Ws[c0+j][kk];
      for (int i=0;i<4;++i) for (int j=0;j<4;++j) acc[i][j] += a[i]*wv[j];
    }
    __syncthreads();
  }
  float w2v = wgt[b*4+2];
  for (int i=0;i<4;++i){
    int n = n0+r0+i;
    float* orow = (n<N1_)? (out + ((size_t)(b*N1_+n))*D_)
                         : (out + (size_t)IMG_OFF + ((size_t)(b*N2_+(n-N1_)))*D_);
    for (int j=0;j<4;++j){
      int d = d0+c0+j;
      orow[d] += w2v*(acc[i][j] + bias[d]);
    }
  }
}

extern "C" void kernel_launch(void* const* d_in, const int* in_sizes, int n_in,
                              void* d_out, int out_size, void* d_ws, size_t ws_size,
                              hipStream_t stream) {
  const float* x1        = (const float*)d_in[0];
  const float* x2        = (const float*)d_in[1];
  const float* r_w1      = (const float*)d_in[2];
  const float* r_b1      = (const float*)d_in[3];
  const float* ln_g      = (const float*)d_in[4];
  const float* ln_b      = (const float*)d_in[5];
  const float* r_w2      = (const float*)d_in[6];
  const float* r_b2      = (const float*)d_in[7];
  const float* lf_w      = (const float*)d_in[8];
  const float* lf_b      = (const float*)d_in[9];
  const float* af2_w     = (const float*)d_in[10];
  const float* af2_b     = (const float*)d_in[11];
  const float* af3_w     = (const float*)d_in[12];
  const float* af3_b     = (const float*)d_in[13];
  const float* attn_in_w = (const float*)d_in[14];
  const float* attn_in_b = (const float*)d_in[15];
  const float* attn_out_w= (const float*)d_in[16];
  const float* attn_out_b= (const float*)d_in[17];
  float* out = (float*)d_out;

  // ws layout: mp[32*8*512 f32] | w[128 f32] | kv[B*S*512 bf16] | obuf[B*S*256 bf16]
  // total = 512KB + 512B + 25.2MB + 12.6MB ~= 38.3 MB
  float* ws_mp = (float*)d_ws;
  float* ws_w  = ws_mp + 131072;
  __hip_bfloat16* ws_kv = (__hip_bfloat16*)(ws_w + 128);
  __hip_bfloat16* ws_ob = ws_kv + (size_t)B_*S_*512;

  k_mean<<<dim3(B_*8), 256, 0, stream>>>(x1, x2, ws_mp);
  k_head<<<dim3(B_), 256, 0, stream>>>(ws_mp, r_w1, r_b1, ln_g, ln_b, r_w2, r_b2, ws_w);
  k_lf  <<<dim3(4,12,B_), 256, 0, stream>>>(x1, x2, lf_w, lf_b, ws_w, out);
  k_xout<<<dim3(4,8,B_),  256, 0, stream>>>(x1, x2, af2_w, af2_b, af3_w, af3_b, ws_w, out);
  k_kv  <<<dim3(8,12,B_), 256, 0, stream>>>(x1, x2, attn_in_w, attn_in_b, ws_kv);
  k_attn<<<dim3(12,8,B_), 256, 0, stream>>>(x1, x2, attn_in_w, attn_in_b, ws_kv, ws_ob);
  k_proj<<<dim3(4,12,B_), 256, 0, stream>>>(ws_ob, attn_out_w, attn_out_b, ws_w, out);
}

// Round 3
// 363.796 us; speedup vs baseline: 4.4452x; 4.4452x over previous
//
#include <hip/hip_runtime.h>
#include <hip/hip_bf16.h>
#include <math.h>

// Problem: SurMoE. B=32, N1=512, N2=256, D=256, H=8, HD=32, S=768.
// Outputs: gene (32,512,256) f32 then img (32,256,256) f32, concat flat.
#define B_ 32
#define N1_ 512
#define N2_ 256
#define D_ 256
#define S_ 768
#define IMG_OFF 4194304  // 32*512*256

typedef __attribute__((ext_vector_type(8))) short bf16x8;
typedef __attribute__((ext_vector_type(4))) float f32x4;
#define MFMA16(a, b, c) __builtin_amdgcn_mfma_f32_16x16x32_bf16(a, b, c, 0, 0, 0)

__device__ __forceinline__ ushort f2b(float f) {
  __hip_bfloat16 h = __float2bfloat16(f);
  return __builtin_bit_cast(ushort, h);
}
__device__ __forceinline__ float eluf(float v) { return v > 0.f ? v : expm1f(v); }

// ---------------- means (deterministic partial sums) ----------------
__global__ __launch_bounds__(256) void k_mean(const float* __restrict__ x1,
                                              const float* __restrict__ x2,
                                              float* __restrict__ mp) {
  int b = blockIdx.x >> 3;
  int s = blockIdx.x & 7;
  int d = threadIdx.x;
  float s1 = 0.f;
  const float* p1 = x1 + ((size_t)(b*N1_ + s*64))*D_ + d;
  for (int n = 0; n < 64; ++n) s1 += p1[(size_t)n*D_];
  float s2 = 0.f;
  const float* p2 = x2 + ((size_t)(b*N2_ + s*32))*D_ + d;
  for (int n = 0; n < 32; ++n) s2 += p2[(size_t)n*D_];
  mp[(size_t)(b*8+s)*512 + d]       = s1 * (1.0f/512.0f);
  mp[(size_t)(b*8+s)*512 + 256 + d] = s2 * (1.0f/256.0f);
}

// ---------------- router head ----------------
__global__ __launch_bounds__(256) void k_head(const float* __restrict__ mp, const float* __restrict__ r_w1,
                       const float* __restrict__ r_b1, const float* __restrict__ ln_g,
                       const float* __restrict__ ln_b, const float* __restrict__ r_w2,
                       const float* __restrict__ r_b2, float* __restrict__ wout) {
  int b = blockIdx.x;
  int j = threadIdx.x;  // 256
  __shared__ float ms[512];
  __shared__ float red[256];
  float a0 = 0.f, a1 = 0.f;
  for (int s = 0; s < 8; ++s) {
    a0 += mp[(size_t)(b*8+s)*512 + j];
    a1 += mp[(size_t)(b*8+s)*512 + 256 + j];
  }
  ms[j] = a0; ms[j+256] = a1;
  __syncthreads();
  float acc = r_b1[j];
  const float* wrow = r_w1 + (size_t)j*512;
  for (int k = 0; k < 512; ++k) acc += ms[k]*wrow[k];
  red[j] = acc; __syncthreads();
  for (int off=128; off>0; off>>=1){ if (j<off) red[j]+=red[j+off]; __syncthreads(); }
  float mu = red[0] * (1.f/256.f); __syncthreads();
  float cd = acc - mu;
  red[j] = cd*cd; __syncthreads();
  for (int off=128; off>0; off>>=1){ if (j<off) red[j]+=red[j+off]; __syncthreads(); }
  float var = red[0]*(1.f/256.f); __syncthreads();
  float xn = cd * rsqrtf(var + 1e-5f) * ln_g[j] + ln_b[j];
  float h = 0.5f*xn*(1.f+erff(xn*0.70710678118654752f));
  float lg[4];
  for (int e=0;e<4;++e){
    red[j] = h * r_w2[e*256 + j]; __syncthreads();
    for (int off=128; off>0; off>>=1){ if (j<off) red[j]+=red[j+off]; __syncthreads(); }
    lg[e] = red[0] + r_b2[e]; __syncthreads();
  }
  if (j==0){
    float mx = fmaxf(fmaxf(lg[0],lg[1]),fmaxf(lg[2],lg[3]));
    float e0=expf(lg[0]-mx),e1=expf(lg[1]-mx),e2=expf(lg[2]-mx),e3=expf(lg[3]-mx);
    float s=e0+e1+e2+e3;
    wout[b*4+0]=e0/s; wout[b*4+1]=e1/s; wout[b*4+2]=e2/s; wout[b*4+3]=e3/s;
  }
}

// ---------------- lf: out = w0*elu(z@lf_w^T + lf_b) + w3*z (writes ALL outputs) ----------------
__global__ __launch_bounds__(256) void k_lf(const float* __restrict__ x1, const float* __restrict__ x2,
                     const float* __restrict__ lf_w, const float* __restrict__ lf_b,
                     const float* __restrict__ wgt, float* __restrict__ out) {
  int dt = blockIdx.x, nt = blockIdx.y, b = blockIdx.z;
  int tid = threadIdx.x;
  int lane = tid & 63, wid = tid >> 6;
  int wm = wid >> 1, wn = wid & 1;
  int l15 = lane & 15, quad = lane >> 4;
  __shared__ __align__(16) ushort As[64][72];
  __shared__ __align__(16) ushort Ws[64][72];
  f32x4 acc[2][2] = {};
  int n0 = nt*64, d0 = dt*64;
  int sr = tid >> 2, scg = (tid & 3) * 16;
  int na = n0 + sr;
  const float* arow = (na < N1_) ? (x1 + ((size_t)(b*N1_+na))*D_)
                                 : (x2 + ((size_t)(b*N2_+(na-N1_)))*D_);
  const float* wrow = lf_w + (size_t)(d0+sr)*D_;
  for (int k0 = 0; k0 < 256; k0 += 64) {
    const float4* pa = (const float4*)(arow + k0 + scg);
    const float4* pw = (const float4*)(wrow + k0 + scg);
    #pragma unroll
    for (int i = 0; i < 4; ++i) {
      float4 va = pa[i];
      *(ushort4*)&As[sr][scg + 4*i] = make_ushort4(f2b(va.x), f2b(va.y), f2b(va.z), f2b(va.w));
      float4 vw = pw[i];
      *(ushort4*)&Ws[sr][scg + 4*i] = make_ushort4(f2b(vw.x), f2b(vw.y), f2b(vw.z), f2b(vw.w));
    }
    __syncthreads();
    #pragma unroll
    for (int kc = 0; kc < 2; ++kc) {
      bf16x8 a0f = *(bf16x8*)&As[wm*32 + l15][kc*32 + quad*8];
      bf16x8 a1f = *(bf16x8*)&As[wm*32 + 16 + l15][kc*32 + quad*8];
      bf16x8 b0f = *(bf16x8*)&Ws[wn*32 + l15][kc*32 + quad*8];
      bf16x8 b1f = *(bf16x8*)&Ws[wn*32 + 16 + l15][kc*32 + quad*8];
      acc[0][0] = MFMA16(a0f, b0f, acc[0][0]);
      acc[0][1] = MFMA16(a0f, b1f, acc[0][1]);
      acc[1][0] = MFMA16(a1f, b0f, acc[1][0]);
      acc[1][1] = MFMA16(a1f, b1f, acc[1][1]);
    }
    __syncthreads();
  }
  float w0 = wgt[b*4+0], w3 = wgt[b*4+3];
  #pragma unroll
  for (int im = 0; im < 2; ++im) {
    #pragma unroll
    for (int reg = 0; reg < 4; ++reg) {
      int n = n0 + wm*32 + im*16 + quad*4 + reg;
      const float* zr = (n<N1_)? x1 + ((size_t)(b*N1_+n))*D_ : x2 + ((size_t)(b*N2_+(n-N1_)))*D_;
      float* orw = (n<N1_)? out + ((size_t)(b*N1_+n))*D_
                          : out + (size_t)IMG_OFF + ((size_t)(b*N2_+(n-N1_)))*D_;
      #pragma unroll
      for (int in = 0; in < 2; ++in) {
        int d = d0 + wn*32 + in*16 + l15;
        float v = acc[im][in][reg] + lf_b[d];
        orw[d] = w0*eluf(v) + w3*zr[d];
      }
    }
  }
}

// ---------------- xout: out += w1*( elu(x1@af2^T+b) + elu(af3@x2[b]+b3[row]) ) ----------------
__global__ __launch_bounds__(256) void k_xout(const float* __restrict__ x1, const float* __restrict__ x2,
                       const float* __restrict__ af2_w, const float* __restrict__ af2_b,
                       const float* __restrict__ af3_w, const float* __restrict__ af3_b,
                       const float* __restrict__ wgt, float* __restrict__ out) {
  int dt = blockIdx.x, nt = blockIdx.y, b = blockIdx.z;
  int tid = threadIdx.x;
  int lane = tid & 63, wid = tid >> 6;
  int wm = wid >> 1, wn = wid & 1;
  int l15 = lane & 15, quad = lane >> 4;
  __shared__ __align__(16) ushort As1[64][72];  // x1 rows [m][k]
  __shared__ __align__(16) ushort Ws1[64][72];  // af2_w rows [d][k]
  __shared__ __align__(16) ushort As2[64][72];  // af3_w rows [p][k=n2]
  __shared__ __align__(16) ushort Ws2[64][72];  // x2^T    [d][k=n2]
  f32x4 acc1[2][2] = {}, acc2[2][2] = {};
  int n0 = nt*64, d0 = dt*64;
  int sr = tid >> 2, scg = (tid & 3) * 16;
  const float* a1row = x1 + ((size_t)(b*N1_ + n0 + sr))*D_;
  const float* w1row = af2_w + (size_t)(d0+sr)*D_;
  const float* a2row = af3_w + (size_t)(n0+sr)*D_;
  for (int k0 = 0; k0 < 256; k0 += 64) {
    const float4* p1 = (const float4*)(a1row + k0 + scg);
    const float4* p2 = (const float4*)(w1row + k0 + scg);
    const float4* p3 = (const float4*)(a2row + k0 + scg);
    const float4* p4 = (const float4*)(x2 + ((size_t)(b*N2_ + k0 + sr))*D_ + d0 + scg);
    #pragma unroll
    for (int i = 0; i < 4; ++i) {
      float4 v1 = p1[i];
      *(ushort4*)&As1[sr][scg + 4*i] = make_ushort4(f2b(v1.x), f2b(v1.y), f2b(v1.z), f2b(v1.w));
      float4 v2 = p2[i];
      *(ushort4*)&Ws1[sr][scg + 4*i] = make_ushort4(f2b(v2.x), f2b(v2.y), f2b(v2.z), f2b(v2.w));
      float4 v3 = p3[i];
      *(ushort4*)&As2[sr][scg + 4*i] = make_ushort4(f2b(v3.x), f2b(v3.y), f2b(v3.z), f2b(v3.w));
      float4 v4 = p4[i];  // transpose-stage into Ws2[d][k]
      Ws2[scg + 4*i + 0][sr] = f2b(v4.x);
      Ws2[scg + 4*i + 1][sr] = f2b(v4.y);
      Ws2[scg + 4*i + 2][sr] = f2b(v4.z);
      Ws2[scg + 4*i + 3][sr] = f2b(v4.w);
    }
    __syncthreads();
    #pragma unroll
    for (int kc = 0; kc < 2; ++kc) {
      bf16x8 a10 = *(bf16x8*)&As1[wm*32 + l15][kc*32 + quad*8];
      bf16x8 a11 = *(bf16x8*)&As1[wm*32 + 16 + l15][kc*32 + quad*8];
      bf16x8 b10 = *(bf16x8*)&Ws1[wn*32 + l15][kc*32 + quad*8];
      bf16x8 b11 = *(bf16x8*)&Ws1[wn*32 + 16 + l15][kc*32 + quad*8];
      acc1[0][0] = MFMA16(a10, b10, acc1[0][0]);
      acc1[0][1] = MFMA16(a10, b11, acc1[0][1]);
      acc1[1][0] = MFMA16(a11, b10, acc1[1][0]);
      acc1[1][1] = MFMA16(a11, b11, acc1[1][1]);
      bf16x8 a20 = *(bf16x8*)&As2[wm*32 + l15][kc*32 + quad*8];
      bf16x8 a21 = *(bf16x8*)&As2[wm*32 + 16 + l15][kc*32 + quad*8];
      bf16x8 b20 = *(bf16x8*)&Ws2[wn*32 + l15][kc*32 + quad*8];
      bf16x8 b21 = *(bf16x8*)&Ws2[wn*32 + 16 + l15][kc*32 + quad*8];
      acc2[0][0] = MFMA16(a20, b20, acc2[0][0]);
      acc2[0][1] = MFMA16(a20, b21, acc2[0][1]);
      acc2[1][0] = MFMA16(a21, b20, acc2[1][0]);
      acc2[1][1] = MFMA16(a21, b21, acc2[1][1]);
    }
    __syncthreads();
  }
  float w1v = wgt[b*4+1];
  #pragma unroll
  for (int im = 0; im < 2; ++im) {
    #pragma unroll
    for (int reg = 0; reg < 4; ++reg) {
      int n = n0 + wm*32 + im*16 + quad*4 + reg;
      float* grow = out + ((size_t)(b*N1_+n))*D_;
      float* irow = (n<N2_)? (out + (size_t)IMG_OFF + ((size_t)(b*N2_+n))*D_) : nullptr;
      float b3 = af3_b[n];
      #pragma unroll
      for (int in = 0; in < 2; ++in) {
        int d = d0 + wn*32 + in*16 + l15;
        float xo = eluf(acc1[im][in][reg] + af2_b[d]) + eluf(acc2[im][in][reg] + b3);
        grow[d] += w1v*xo;
        if (irow) irow[d] += w1v*xo;
      }
    }
  }
}

// ---------------- qkv: q,k -> [b][n][256] bf16; v -> vT[b][h][32][768] bf16 ----------------
__global__ __launch_bounds__(256) void k_qkv(const float* __restrict__ x1, const float* __restrict__ x2,
                      const float* __restrict__ w, const float* __restrict__ bias,
                      ushort* __restrict__ qws, ushort* __restrict__ kws,
                      ushort* __restrict__ vtws) {
  int ct = blockIdx.x, nt = blockIdx.y, b = blockIdx.z;
  int tid = threadIdx.x;
  int lane = tid & 63, wid = tid >> 6;
  int wm = wid >> 1, wn = wid & 1;
  int l15 = lane & 15, quad = lane >> 4;
  __shared__ __align__(16) ushort As[64][72];
  __shared__ __align__(16) ushort Ws[64][72];
  f32x4 acc[2][2] = {};
  int n0 = nt*64, c0b = ct*64;
  int sr = tid >> 2, scg = (tid & 3) * 16;
  int na = n0 + sr;
  const float* arow = (na < N1_) ? (x1 + ((size_t)(b*N1_+na))*D_)
                                 : (x2 + ((size_t)(b*N2_+(na-N1_)))*D_);
  const float* wrow = w + (size_t)(c0b+sr)*D_;
  for (int k0 = 0; k0 < 256; k0 += 64) {
    const float4* pa = (const float4*)(arow + k0 + scg);
    const float4* pw = (const float4*)(wrow + k0 + scg);
    #pragma unroll
    for (int i = 0; i < 4; ++i) {
      float4 va = pa[i];
      *(ushort4*)&As[sr][scg + 4*i] = make_ushort4(f2b(va.x), f2b(va.y), f2b(va.z), f2b(va.w));
      float4 vw = pw[i];
      *(ushort4*)&Ws[sr][scg + 4*i] = make_ushort4(f2b(vw.x), f2b(vw.y), f2b(vw.z), f2b(vw.w));
    }
    __syncthreads();
    #pragma unroll
    for (int kc = 0; kc < 2; ++kc) {
      bf16x8 a0f = *(bf16x8*)&As[wm*32 + l15][kc*32 + quad*8];
      bf16x8 a1f = *(bf16x8*)&As[wm*32 + 16 + l15][kc*32 + quad*8];
      bf16x8 b0f = *(bf16x8*)&Ws[wn*32 + l15][kc*32 + quad*8];
      bf16x8 b1f = *(bf16x8*)&Ws[wn*32 + 16 + l15][kc*32 + quad*8];
      acc[0][0] = MFMA16(a0f, b0f, acc[0][0]);
      acc[0][1] = MFMA16(a0f, b1f, acc[0][1]);
      acc[1][0] = MFMA16(a1f, b0f, acc[1][0]);
      acc[1][1] = MFMA16(a1f, b1f, acc[1][1]);
    }
    __syncthreads();
  }
  if (ct < 8) {
    ushort* dst = (ct < 4) ? qws : kws;
    int coff = (ct < 4) ? 0 : 256;
    #pragma unroll
    for (int im = 0; im < 2; ++im) {
      #pragma unroll
      for (int reg = 0; reg < 4; ++reg) {
        int n = n0 + wm*32 + im*16 + quad*4 + reg;
        #pragma unroll
        for (int in = 0; in < 2; ++in) {
          int c = c0b + wn*32 + in*16 + l15;
          dst[((size_t)(b*S_)+n)*256 + (c - coff)] = f2b(acc[im][in][reg] + bias[c]);
        }
      }
    }
  } else {
    #pragma unroll
    for (int im = 0; im < 2; ++im) {
      int nb = n0 + wm*32 + im*16 + quad*4;
      #pragma unroll
      for (int in = 0; in < 2; ++in) {
        int c = c0b + wn*32 + in*16 + l15;
        float bs = bias[c];
        int vcol = c - 512;
        int h = vcol >> 5, d = vcol & 31;
        uint2 pk;
        pk.x = (uint)f2b(acc[im][in][0] + bs) | ((uint)f2b(acc[im][in][1] + bs) << 16);
        pk.y = (uint)f2b(acc[im][in][2] + bs) | ((uint)f2b(acc[im][in][3] + bs) << 16);
        *(uint2*)&vtws[(((size_t)(b*8+h))*32 + d)*S_ + nb] = pk;
      }
    }
  }
}

// ---------------- MFMA flash attention per (b,h,qtile=64) ----------------
__global__ __launch_bounds__(256) void k_attn(const ushort* __restrict__ qws,
                                              const ushort* __restrict__ kws,
                                              const ushort* __restrict__ vtws,
                                              ushort* __restrict__ obuf) {
  int qt = blockIdx.x, h = blockIdx.y, b = blockIdx.z;
  int tid = threadIdx.x;
  int lane = tid & 63, w = tid >> 6;
  int l15 = lane & 15, quad = lane >> 4;
  __shared__ __align__(16) ushort Ks[64][40];
  __shared__ __align__(16) ushort Vts[32][72];
  __shared__ __align__(16) ushort Ps[4][64][20];
  __shared__ float als[4][16];
  __shared__ float lls[4][16];

  int qn = qt*64 + w*16 + l15;
  bf16x8 aq = *(const bf16x8*)(qws + ((size_t)(b*S_)+qn)*256 + h*32 + quad*8);

  f32x4 ao[2] = {};
  float m_run[4], l_run[4];
  #pragma unroll
  for (int r = 0; r < 4; ++r) { m_run[r] = -INFINITY; l_run[r] = 0.f; }
  const float scale = 0.17677669529663689f;

  int skr = tid >> 2, skc = (tid & 3) * 8;
  int svd = tid >> 3, svn = (tid & 7) * 8;

  for (int kt = 0; kt < 12; ++kt) {
    __syncthreads();
    *(uint4*)&Ks[skr][skc] =
        *(const uint4*)(kws + ((size_t)(b*S_) + kt*64 + skr)*256 + h*32 + skc);
    *(uint4*)&Vts[svd][svn] =
        *(const uint4*)(vtws + (((size_t)(b*8+h))*32 + svd)*S_ + kt*64 + svn);
    __syncthreads();

    // QK^T: S[q=quad*4+reg][c=16t+l15]
    f32x4 sf[4];
    #pragma unroll
    for (int t = 0; t < 4; ++t) {
      bf16x8 bk = *(bf16x8*)&Ks[t*16 + l15][quad*8];
      f32x4 z = {0.f, 0.f, 0.f, 0.f};
      sf[t] = MFMA16(aq, bk, z);
    }
    #pragma unroll
    for (int t = 0; t < 4; ++t)
      #pragma unroll
      for (int r = 0; r < 4; ++r) sf[t][r] *= scale;

    // online softmax (per q-row = quad*4+reg)
    float al[4];
    #pragma unroll
    for (int r = 0; r < 4; ++r) {
      float m0 = fmaxf(fmaxf(sf[0][r], sf[1][r]), fmaxf(sf[2][r], sf[3][r]));
      m0 = fmaxf(m0, __shfl_xor(m0, 1, 64));
      m0 = fmaxf(m0, __shfl_xor(m0, 2, 64));
      m0 = fmaxf(m0, __shfl_xor(m0, 4, 64));
      m0 = fmaxf(m0, __shfl_xor(m0, 8, 64));
      float mnew = fmaxf(m_run[r], m0);
      al[r] = __expf(m_run[r] - mnew);
      m_run[r] = mnew;
    }
    float lsum[4] = {0.f, 0.f, 0.f, 0.f};
    ushort pu[4][4];
    #pragma unroll
    for (int t = 0; t < 4; ++t)
      #pragma unroll
      for (int r = 0; r < 4; ++r) {
        float p = __expf(sf[t][r] - m_run[r]);
        lsum[r] += p;
        pu[t][r] = f2b(p);
      }
    #pragma unroll
    for (int r = 0; r < 4; ++r) {
      float ls = lsum[r];
      ls += __shfl_xor(ls, 1, 64);
      ls += __shfl_xor(ls, 2, 64);
      ls += __shfl_xor(ls, 4, 64);
      ls += __shfl_xor(ls, 8, 64);
      l_run[r] = l_run[r]*al[r] + ls;
    }
    // write P^T tile: Ps[c][q], packed 4 q per b64
    #pragma unroll
    for (int t = 0; t < 4; ++t) {
      uint2 pk;
      pk.x = (uint)pu[t][0] | ((uint)pu[t][1] << 16);
      pk.y = (uint)pu[t][2] | ((uint)pu[t][3] << 16);
      *(uint2*)&Ps[w][t*16 + l15][quad*4] = pk;
    }
    // broadcast alpha per q (per-wave region; same-wave LDS, no barrier needed)
    if (l15 < 4) als[w][quad*4 + l15] = al[l15];
    float alpha_q = als[w][l15];
    #pragma unroll
    for (int e = 0; e < 4; ++e) { ao[0][e] *= alpha_q; ao[1][e] *= alpha_q; }
    // PV as V^T * P^T: D[d=quad*4+reg(+16*im)][q=l15]
    #pragma unroll
    for (int kc = 0; kc < 2; ++kc) {
      bf16x8 bp;
      #pragma unroll
      for (int j = 0; j < 8; ++j) bp[j] = (short)Ps[w][kc*32 + quad*8 + j][l15];
      bf16x8 av0 = *(bf16x8*)&Vts[l15][kc*32 + quad*8];
      bf16x8 av1 = *(bf16x8*)&Vts[16 + l15][kc*32 + quad*8];
      ao[0] = MFMA16(av0, bp, ao[0]);
      ao[1] = MFMA16(av1, bp, ao[1]);
    }
  }
  if (l15 < 4) lls[w][quad*4 + l15] = l_run[l15];
  float linv = 1.f / lls[w][l15];
  int n = qt*64 + w*16 + l15;
  #pragma unroll
  for (int im = 0; im < 2; ++im) {
    uint2 pk;
    pk.x = (uint)f2b(ao[im][0]*linv) | ((uint)f2b(ao[im][1]*linv) << 16);
    pk.y = (uint)f2b(ao[im][2]*linv) | ((uint)f2b(ao[im][3]*linv) << 16);
    *(uint2*)&obuf[((size_t)(b*S_)+n)*256 + h*32 + im*16 + quad*4] = pk;
  }
}

// ---------------- proj: out += w2*(o @ attn_out_w^T + attn_out_b) ----------------
__global__ __launch_bounds__(256) void k_proj(const ushort* __restrict__ obuf, const float* __restrict__ w,
                       const float* __restrict__ bias, const float* __restrict__ wgt,
                       float* __restrict__ out) {
  int dt = blockIdx.x, nt = blockIdx.y, b = blockIdx.z;
  int tid = threadIdx.x;
  int lane = tid & 63, wid = tid >> 6;
  int wm = wid >> 1, wn = wid & 1;
  int l15 = lane & 15, quad = lane >> 4;
  __shared__ __align__(16) ushort As[64][72];
  __shared__ __align__(16) ushort Ws[64][72];
  f32x4 acc[2][2] = {};
  int n0 = nt*64, d0 = dt*64;
  int sr = tid >> 2, scg = (tid & 3) * 16;
  const ushort* arow = obuf + ((size_t)(b*S_) + n0 + sr)*256;
  const float* wrow = w + (size_t)(d0+sr)*D_;
  for (int k0 = 0; k0 < 256; k0 += 64) {
    const uint4* pa = (const uint4*)(arow + k0 + scg);
    *(uint4*)&As[sr][scg]     = pa[0];
    *(uint4*)&As[sr][scg + 8] = pa[1];
    const float4* pw = (const float4*)(wrow + k0 + scg);
    #pragma unroll
    for (int i = 0; i < 4; ++i) {
      float4 vw = pw[i];
      *(ushort4*)&Ws[sr][scg + 4*i] = make_ushort4(f2b(vw.x), f2b(vw.y), f2b(vw.z), f2b(vw.w));
    }
    __syncthreads();
    #pragma unroll
    for (int kc = 0; kc < 2; ++kc) {
      bf16x8 a0f = *(bf16x8*)&As[wm*32 + l15][kc*32 + quad*8];
      bf16x8 a1f = *(bf16x8*)&As[wm*32 + 16 + l15][kc*32 + quad*8];
      bf16x8 b0f = *(bf16x8*)&Ws[wn*32 + l15][kc*32 + quad*8];
      bf16x8 b1f = *(bf16x8*)&Ws[wn*32 + 16 + l15][kc*32 + quad*8];
      acc[0][0] = MFMA16(a0f, b0f, acc[0][0]);
      acc[0][1] = MFMA16(a0f, b1f, acc[0][1]);
      acc[1][0] = MFMA16(a1f, b0f, acc[1][0]);
      acc[1][1] = MFMA16(a1f, b1f, acc[1][1]);
    }
    __syncthreads();
  }
  float w2v = wgt[b*4+2];
  #pragma unroll
  for (int im = 0; im < 2; ++im) {
    #pragma unroll
    for (int reg = 0; reg < 4; ++reg) {
      int n = n0 + wm*32 + im*16 + quad*4 + reg;
      float* orw = (n<N1_)? out + ((size_t)(b*N1_+n))*D_
                          : out + (size_t)IMG_OFF + ((size_t)(b*N2_+(n-N1_)))*D_;
      #pragma unroll
      for (int in = 0; in < 2; ++in) {
        int d = d0 + wn*32 + in*16 + l15;
        orw[d] += w2v*(acc[im][in][reg] + bias[d]);
      }
    }
  }
}

extern "C" void kernel_launch(void* const* d_in, const int* in_sizes, int n_in,
                              void* d_out, int out_size, void* d_ws, size_t ws_size,
                              hipStream_t stream) {
  const float* x1        = (const float*)d_in[0];
  const float* x2        = (const float*)d_in[1];
  const float* r_w1      = (const float*)d_in[2];
  const float* r_b1      = (const float*)d_in[3];
  const float* ln_g      = (const float*)d_in[4];
  const float* ln_b      = (const float*)d_in[5];
  const float* r_w2      = (const float*)d_in[6];
  const float* r_b2      = (const float*)d_in[7];
  const float* lf_w      = (const float*)d_in[8];
  const float* lf_b      = (const float*)d_in[9];
  const float* af2_w     = (const float*)d_in[10];
  const float* af2_b     = (const float*)d_in[11];
  const float* af3_w     = (const float*)d_in[12];
  const float* af3_b     = (const float*)d_in[13];
  const float* attn_in_w = (const float*)d_in[14];
  const float* attn_in_b = (const float*)d_in[15];
  const float* attn_out_w= (const float*)d_in[16];
  const float* attn_out_b= (const float*)d_in[17];
  float* out = (float*)d_out;

  // ws layout: mp[32*8*512 f32] | w[128 f32] | qo[B*S*256 ush] | k[B*S*256 ush] | vT[B*8*32*S ush]
  // total = 524800 B + 3 * 12582912 B ~= 38.3 MB (q region doubles as attention output)
  float* ws_mp = (float*)d_ws;
  float* ws_w  = ws_mp + 131072;
  ushort* ws_qo = (ushort*)(ws_w + 128);
  ushort* ws_k  = ws_qo + (size_t)B_*S_*256;
  ushort* ws_vt = ws_k  + (size_t)B_*S_*256;

  k_mean<<<dim3(B_*8), 256, 0, stream>>>(x1, x2, ws_mp);
  k_head<<<dim3(B_), 256, 0, stream>>>(ws_mp, r_w1, r_b1, ln_g, ln_b, r_w2, r_b2, ws_w);
  k_lf  <<<dim3(4,12,B_), 256, 0, stream>>>(x1, x2, lf_w, lf_b, ws_w, out);
  k_xout<<<dim3(4,8,B_),  256, 0, stream>>>(x1, x2, af2_w, af2_b, af3_w, af3_b, ws_w, out);
  k_qkv <<<dim3(12,12,B_),256, 0, stream>>>(x1, x2, attn_in_w, attn_in_b, ws_qo, ws_k, ws_vt);
  k_attn<<<dim3(12,8,B_), 256, 0, stream>>>(ws_qo, ws_k, ws_vt, ws_qo);
  k_proj<<<dim3(4,12,B_), 256, 0, stream>>>(ws_qo, attn_out_w, attn_out_b, ws_w, out);
}

// Round 4
// 285.700 us; speedup vs baseline: 5.6603x; 1.2734x over previous
//
#include <hip/hip_runtime.h>
#include <hip/hip_bf16.h>
#include <math.h>

// Problem: SurMoE. B=32, N1=512, N2=256, D=256, H=8, HD=32, S=768.
// Outputs: gene (32,512,256) f32 then img (32,256,256) f32, concat flat.
#define B_ 32
#define N1_ 512
#define N2_ 256
#define D_ 256
#define S_ 768
#define IMG_OFF 4194304  // 32*512*256
#define SCALE_ 0.17677669529663689f

typedef __attribute__((ext_vector_type(8))) short bf16x8;
typedef __attribute__((ext_vector_type(4))) float f32x4;
#define MFMA16(a, b, c) __builtin_amdgcn_mfma_f32_16x16x32_bf16(a, b, c, 0, 0, 0)

__device__ __forceinline__ ushort f2b(float f) {
  __hip_bfloat16 h = __float2bfloat16(f);
  return __builtin_bit_cast(ushort, h);
}
__device__ __forceinline__ float eluf(float v) { return v > 0.f ? v : expm1f(v); }

// ---------------- f32 -> bf16 conversion of z = x1||x2 (per batch) ----------------
// j indexes uint4 outputs (8 elems); shift: log2(uint4s per batch section)
__global__ __launch_bounds__(256) void k_cvt(const float* __restrict__ src,
                                             ushort* __restrict__ zb,
                                             int shift, int boff) {
  int j = blockIdx.x*256 + threadIdx.x;
  int b = j >> shift;
  int rj = j & ((1 << shift) - 1);
  const float4* s = (const float4*)src + (size_t)j*2;
  float4 v0 = s[0], v1 = s[1];
  uint4 pk;
  pk.x = (uint)f2b(v0.x) | ((uint)f2b(v0.y) << 16);
  pk.y = (uint)f2b(v0.z) | ((uint)f2b(v0.w) << 16);
  pk.z = (uint)f2b(v1.x) | ((uint)f2b(v1.y) << 16);
  pk.w = (uint)f2b(v1.z) | ((uint)f2b(v1.w) << 16);
  *(uint4*)(zb + (size_t)b*196608 + boff + (size_t)rj*8) = pk;
}

// ---------------- weights -> bf16 (Wq prescaled by 1/sqrt(HD)) ----------------
// wb layout (elems): lf[0,64K) af2[64K,128K) af3[128K,256K) attn_in[256K,448K) attn_out[448K,512K)
__global__ __launch_bounds__(256) void k_wcvt(const float* __restrict__ lf_w,
                                              const float* __restrict__ af2_w,
                                              const float* __restrict__ af3_w,
                                              const float* __restrict__ attn_in_w,
                                              const float* __restrict__ attn_out_w,
                                              ushort* __restrict__ wb) {
  int g = blockIdx.x*256 + threadIdx.x;
  int e0 = g*4;
  const float* src; int loc; float sc = 1.f;
  if (e0 < 65536)       { src = lf_w;       loc = e0; }
  else if (e0 < 131072) { src = af2_w;      loc = e0 - 65536; }
  else if (e0 < 262144) { src = af3_w;      loc = e0 - 131072; }
  else if (e0 < 458752) { src = attn_in_w;  loc = e0 - 262144; if (loc < 65536) sc = SCALE_; }
  else                  { src = attn_out_w; loc = e0 - 458752; }
  float4 v = *(const float4*)(src + loc);
  *(ushort4*)(wb + e0) = make_ushort4(f2b(v.x*sc), f2b(v.y*sc), f2b(v.z*sc), f2b(v.w*sc));
}

// ---------------- means (deterministic partial sums) ----------------
__global__ __launch_bounds__(256) void k_mean(const float* __restrict__ x1,
                                              const float* __restrict__ x2,
                                              float* __restrict__ mp) {
  int b = blockIdx.x >> 3;
  int s = blockIdx.x & 7;
  int d = threadIdx.x;
  float s1 = 0.f;
  const float* p1 = x1 + ((size_t)(b*N1_ + s*64))*D_ + d;
  for (int n = 0; n < 64; ++n) s1 += p1[(size_t)n*D_];
  float s2 = 0.f;
  const float* p2 = x2 + ((size_t)(b*N2_ + s*32))*D_ + d;
  for (int n = 0; n < 32; ++n) s2 += p2[(size_t)n*D_];
  mp[(size_t)(b*8+s)*512 + d]       = s1 * (1.0f/512.0f);
  mp[(size_t)(b*8+s)*512 + 256 + d] = s2 * (1.0f/256.0f);
}

// ---------------- router head ----------------
__global__ __launch_bounds__(256) void k_head(const float* __restrict__ mp, const float* __restrict__ r_w1,
                       const float* __restrict__ r_b1, const float* __restrict__ ln_g,
                       const float* __restrict__ ln_b, const float* __restrict__ r_w2,
                       const float* __restrict__ r_b2, float* __restrict__ wout) {
  int b = blockIdx.x;
  int j = threadIdx.x;  // 256
  __shared__ float ms[512];
  __shared__ float red[256];
  float a0 = 0.f, a1 = 0.f;
  for (int s = 0; s < 8; ++s) {
    a0 += mp[(size_t)(b*8+s)*512 + j];
    a1 += mp[(size_t)(b*8+s)*512 + 256 + j];
  }
  ms[j] = a0; ms[j+256] = a1;
  __syncthreads();
  float acc = r_b1[j];
  const float* wrow = r_w1 + (size_t)j*512;
  for (int k = 0; k < 512; ++k) acc += ms[k]*wrow[k];
  red[j] = acc; __syncthreads();
  for (int off=128; off>0; off>>=1){ if (j<off) red[j]+=red[j+off]; __syncthreads(); }
  float mu = red[0] * (1.f/256.f); __syncthreads();
  float cd = acc - mu;
  red[j] = cd*cd; __syncthreads();
  for (int off=128; off>0; off>>=1){ if (j<off) red[j]+=red[j+off]; __syncthreads(); }
  float var = red[0]*(1.f/256.f); __syncthreads();
  float xn = cd * rsqrtf(var + 1e-5f) * ln_g[j] + ln_b[j];
  float h = 0.5f*xn*(1.f+erff(xn*0.70710678118654752f));
  float lg[4];
  for (int e=0;e<4;++e){
    red[j] = h * r_w2[e*256 + j]; __syncthreads();
    for (int off=128; off>0; off>>=1){ if (j<off) red[j]+=red[j+off]; __syncthreads(); }
    lg[e] = red[0] + r_b2[e]; __syncthreads();
  }
  if (j==0){
    float mx = fmaxf(fmaxf(lg[0],lg[1]),fmaxf(lg[2],lg[3]));
    float e0=expf(lg[0]-mx),e1=expf(lg[1]-mx),e2=expf(lg[2]-mx),e3=expf(lg[3]-mx);
    float s=e0+e1+e2+e3;
    wout[b*4+0]=e0/s; wout[b*4+1]=e1/s; wout[b*4+2]=e2/s; wout[b*4+3]=e3/s;
  }
}

// ---------------- lf: out = w0*elu(z@lf_w^T + lf_b) + w3*z (writes ALL outputs) ----------------
__global__ __launch_bounds__(256) void k_lf(const ushort* __restrict__ zb, const ushort* __restrict__ wb,
                     const float* __restrict__ x1, const float* __restrict__ x2,
                     const float* __restrict__ lf_b,
                     const float* __restrict__ wgt, float* __restrict__ out) {
  int dt = blockIdx.x, nt = blockIdx.y, b = blockIdx.z;
  int tid = threadIdx.x;
  int lane = tid & 63, wid = tid >> 6;
  int wm = wid >> 1, wn = wid & 1;
  int l15 = lane & 15, quad = lane >> 4;
  __shared__ __align__(16) ushort As[64][72];
  __shared__ __align__(16) ushort Ws[64][72];
  f32x4 acc[2][2] = {};
  int n0 = nt*64, d0 = dt*64;
  int sr = tid >> 2, scg = (tid & 3) * 16;
  const ushort* arow = zb + (size_t)b*196608 + (size_t)(n0+sr)*256;
  const ushort* wrow = wb + (size_t)(d0+sr)*256;   // lf region at offset 0
  for (int k0 = 0; k0 < 256; k0 += 64) {
    *(uint4*)&As[sr][scg]   = *(const uint4*)(arow + k0 + scg);
    *(uint4*)&As[sr][scg+8] = *(const uint4*)(arow + k0 + scg + 8);
    *(uint4*)&Ws[sr][scg]   = *(const uint4*)(wrow + k0 + scg);
    *(uint4*)&Ws[sr][scg+8] = *(const uint4*)(wrow + k0 + scg + 8);
    __syncthreads();
    #pragma unroll
    for (int kc = 0; kc < 2; ++kc) {
      bf16x8 a0f = *(bf16x8*)&As[wm*32 + l15][kc*32 + quad*8];
      bf16x8 a1f = *(bf16x8*)&As[wm*32 + 16 + l15][kc*32 + quad*8];
      bf16x8 b0f = *(bf16x8*)&Ws[wn*32 + l15][kc*32 + quad*8];
      bf16x8 b1f = *(bf16x8*)&Ws[wn*32 + 16 + l15][kc*32 + quad*8];
      acc[0][0] = MFMA16(a0f, b0f, acc[0][0]);
      acc[0][1] = MFMA16(a0f, b1f, acc[0][1]);
      acc[1][0] = MFMA16(a1f, b0f, acc[1][0]);
      acc[1][1] = MFMA16(a1f, b1f, acc[1][1]);
    }
    __syncthreads();
  }
  float w0 = wgt[b*4+0], w3 = wgt[b*4+3];
  #pragma unroll
  for (int im = 0; im < 2; ++im) {
    #pragma unroll
    for (int reg = 0; reg < 4; ++reg) {
      int n = n0 + wm*32 + im*16 + quad*4 + reg;
      const float* zr = (n<N1_)? x1 + ((size_t)(b*N1_+n))*D_ : x2 + ((size_t)(b*N2_+(n-N1_)))*D_;
      float* orw = (n<N1_)? out + ((size_t)(b*N1_+n))*D_
                          : out + (size_t)IMG_OFF + ((size_t)(b*N2_+(n-N1_)))*D_;
      #pragma unroll
      for (int in = 0; in < 2; ++in) {
        int d = d0 + wn*32 + in*16 + l15;
        float v = acc[im][in][reg] + lf_b[d];
        orw[d] = w0*eluf(v) + w3*zr[d];
      }
    }
  }
}

// ---------------- xout: out += w1*( elu(x1@af2^T+b) + elu(af3@x2[b]+b3[row]) ) ----------------
__global__ __launch_bounds__(256) void k_xout(const ushort* __restrict__ zb, const ushort* __restrict__ wb,
                       const float* __restrict__ af2_b, const float* __restrict__ af3_b,
                       const float* __restrict__ wgt, float* __restrict__ out) {
  int dt = blockIdx.x, nt = blockIdx.y, b = blockIdx.z;
  int tid = threadIdx.x;
  int lane = tid & 63, wid = tid >> 6;
  int wm = wid >> 1, wn = wid & 1;
  int l15 = lane & 15, quad = lane >> 4;
  __shared__ __align__(16) ushort As1[64][72];  // x1 rows [m][k]
  __shared__ __align__(16) ushort Ws1[64][72];  // af2_w rows [d][k]
  __shared__ __align__(16) ushort As2[64][72];  // af3_w rows [p][k=n2]
  __shared__ __align__(16) ushort Ws2[64][72];  // x2^T    [d][k=n2]
  f32x4 acc1[2][2] = {}, acc2[2][2] = {};
  int n0 = nt*64, d0 = dt*64;
  int sr = tid >> 2, scg = (tid & 3) * 16;
  const ushort* a1row = zb + (size_t)b*196608 + (size_t)(n0+sr)*256;          // x1 part
  const ushort* w1row = wb + 65536 + (size_t)(d0+sr)*256;                     // af2
  const ushort* a2row = wb + 131072 + (size_t)(n0+sr)*256;                    // af3
  for (int k0 = 0; k0 < 256; k0 += 64) {
    *(uint4*)&As1[sr][scg]   = *(const uint4*)(a1row + k0 + scg);
    *(uint4*)&As1[sr][scg+8] = *(const uint4*)(a1row + k0 + scg + 8);
    *(uint4*)&Ws1[sr][scg]   = *(const uint4*)(w1row + k0 + scg);
    *(uint4*)&Ws1[sr][scg+8] = *(const uint4*)(w1row + k0 + scg + 8);
    *(uint4*)&As2[sr][scg]   = *(const uint4*)(a2row + k0 + scg);
    *(uint4*)&As2[sr][scg+8] = *(const uint4*)(a2row + k0 + scg + 8);
    {  // transpose-stage x2 tile: Ws2[d-local][n2-local]
      const ushort* x2r = zb + (size_t)b*196608 + 131072 + (size_t)(k0+sr)*256 + d0 + scg;
      uint4 va = *(const uint4*)x2r;
      uint4 vb = *(const uint4*)(x2r + 8);
      const ushort* ea = (const ushort*)&va;
      const ushort* eb = (const ushort*)&vb;
      #pragma unroll
      for (int i = 0; i < 8; ++i) Ws2[scg + i][sr] = ea[i];
      #pragma unroll
      for (int i = 0; i < 8; ++i) Ws2[scg + 8 + i][sr] = eb[i];
    }
    __syncthreads();
    #pragma unroll
    for (int kc = 0; kc < 2; ++kc) {
      bf16x8 a10 = *(bf16x8*)&As1[wm*32 + l15][kc*32 + quad*8];
      bf16x8 a11 = *(bf16x8*)&As1[wm*32 + 16 + l15][kc*32 + quad*8];
      bf16x8 b10 = *(bf16x8*)&Ws1[wn*32 + l15][kc*32 + quad*8];
      bf16x8 b11 = *(bf16x8*)&Ws1[wn*32 + 16 + l15][kc*32 + quad*8];
      acc1[0][0] = MFMA16(a10, b10, acc1[0][0]);
      acc1[0][1] = MFMA16(a10, b11, acc1[0][1]);
      acc1[1][0] = MFMA16(a11, b10, acc1[1][0]);
      acc1[1][1] = MFMA16(a11, b11, acc1[1][1]);
      bf16x8 a20 = *(bf16x8*)&As2[wm*32 + l15][kc*32 + quad*8];
      bf16x8 a21 = *(bf16x8*)&As2[wm*32 + 16 + l15][kc*32 + quad*8];
      bf16x8 b20 = *(bf16x8*)&Ws2[wn*32 + l15][kc*32 + quad*8];
      bf16x8 b21 = *(bf16x8*)&Ws2[wn*32 + 16 + l15][kc*32 + quad*8];
      acc2[0][0] = MFMA16(a20, b20, acc2[0][0]);
      acc2[0][1] = MFMA16(a20, b21, acc2[0][1]);
      acc2[1][0] = MFMA16(a21, b20, acc2[1][0]);
      acc2[1][1] = MFMA16(a21, b21, acc2[1][1]);
    }
    __syncthreads();
  }
  float w1v = wgt[b*4+1];
  #pragma unroll
  for (int im = 0; im < 2; ++im) {
    #pragma unroll
    for (int reg = 0; reg < 4; ++reg) {
      int n = n0 + wm*32 + im*16 + quad*4 + reg;
      float* grow = out + ((size_t)(b*N1_+n))*D_;
      float* irow = (n<N2_)? (out + (size_t)IMG_OFF + ((size_t)(b*N2_+n))*D_) : nullptr;
      float b3 = af3_b[n];
      #pragma unroll
      for (int in = 0; in < 2; ++in) {
        int d = d0 + wn*32 + in*16 + l15;
        float xo = eluf(acc1[im][in][reg] + af2_b[d]) + eluf(acc2[im][in][reg] + b3);
        grow[d] += w1v*xo;
        if (irow) irow[d] += w1v*xo;
      }
    }
  }
}

// ---------------- qkv: q(prescaled),k -> [b][n][256] bf16; v -> vT[b][h][32][768] ----------------
__global__ __launch_bounds__(256) void k_qkv(const ushort* __restrict__ zb, const ushort* __restrict__ wb,
                      const float* __restrict__ bias,
                      ushort* __restrict__ qws, ushort* __restrict__ kws,
                      ushort* __restrict__ vtws) {
  int ct = blockIdx.x, nt = blockIdx.y, b = blockIdx.z;
  int tid = threadIdx.x;
  int lane = tid & 63, wid = tid >> 6;
  int wm = wid >> 1, wn = wid & 1;
  int l15 = lane & 15, quad = lane >> 4;
  __shared__ __align__(16) ushort As[64][72];
  __shared__ __align__(16) ushort Ws[64][72];
  f32x4 acc[2][2] = {};
  int n0 = nt*64, c0b = ct*64;
  int sr = tid >> 2, scg = (tid & 3) * 16;
  const ushort* arow = zb + (size_t)b*196608 + (size_t)(n0+sr)*256;
  const ushort* wrow = wb + 262144 + (size_t)(c0b+sr)*256;   // attn_in region
  for (int k0 = 0; k0 < 256; k0 += 64) {
    *(uint4*)&As[sr][scg]   = *(const uint4*)(arow + k0 + scg);
    *(uint4*)&As[sr][scg+8] = *(const uint4*)(arow + k0 + scg + 8);
    *(uint4*)&Ws[sr][scg]   = *(const uint4*)(wrow + k0 + scg);
    *(uint4*)&Ws[sr][scg+8] = *(const uint4*)(wrow + k0 + scg + 8);
    __syncthreads();
    #pragma unroll
    for (int kc = 0; kc < 2; ++kc) {
      bf16x8 a0f = *(bf16x8*)&As[wm*32 + l15][kc*32 + quad*8];
      bf16x8 a1f = *(bf16x8*)&As[wm*32 + 16 + l15][kc*32 + quad*8];
      bf16x8 b0f = *(bf16x8*)&Ws[wn*32 + l15][kc*32 + quad*8];
      bf16x8 b1f = *(bf16x8*)&Ws[wn*32 + 16 + l15][kc*32 + quad*8];
      acc[0][0] = MFMA16(a0f, b0f, acc[0][0]);
      acc[0][1] = MFMA16(a0f, b1f, acc[0][1]);
      acc[1][0] = MFMA16(a1f, b0f, acc[1][0]);
      acc[1][1] = MFMA16(a1f, b1f, acc[1][1]);
    }
    __syncthreads();
  }
  if (ct < 8) {
    ushort* dst = (ct < 4) ? qws : kws;
    int coff = (ct < 4) ? 0 : 256;
    float bsc = (ct < 4) ? SCALE_ : 1.f;   // q is prescaled (W prescaled; bias scaled here)
    #pragma unroll
    for (int im = 0; im < 2; ++im) {
      #pragma unroll
      for (int reg = 0; reg < 4; ++reg) {
        int n = n0 + wm*32 + im*16 + quad*4 + reg;
        #pragma unroll
        for (int in = 0; in < 2; ++in) {
          int c = c0b + wn*32 + in*16 + l15;
          dst[((size_t)(b*S_)+n)*256 + (c - coff)] = f2b(acc[im][in][reg] + bias[c]*bsc);
        }
      }
    }
  } else {
    #pragma unroll
    for (int im = 0; im < 2; ++im) {
      int nb = n0 + wm*32 + im*16 + quad*4;
      #pragma unroll
      for (int in = 0; in < 2; ++in) {
        int c = c0b + wn*32 + in*16 + l15;
        float bs = bias[c];
        int vcol = c - 512;
        int h = vcol >> 5, d = vcol & 31;
        uint2 pk;
        pk.x = (uint)f2b(acc[im][in][0] + bs) | ((uint)f2b(acc[im][in][1] + bs) << 16);
        pk.y = (uint)f2b(acc[im][in][2] + bs) | ((uint)f2b(acc[im][in][3] + bs) << 16);
        *(uint2*)&vtws[(((size_t)(b*8+h))*32 + d)*S_ + nb] = pk;
      }
    }
  }
}

// ---------------- MFMA flash attention, S^T-form, 128 q-rows per block ----------------
__global__ __launch_bounds__(256) void k_attn(const ushort* __restrict__ qws,
                                              const ushort* __restrict__ kws,
                                              const ushort* __restrict__ vtws,
                                              ushort* __restrict__ obuf) {
  int qt = blockIdx.x, h = blockIdx.y, b = blockIdx.z;
  int tid = threadIdx.x;
  int lane = tid & 63, w = tid >> 6;
  int l15 = lane & 15, quad = lane >> 4;
  __shared__ __align__(16) ushort Ks[64][40];
  __shared__ __align__(16) ushort Vts[32][72];
  __shared__ __align__(16) ushort Ps[4][16][72];

  // Q b-frags (q prescaled by 1/sqrt(HD) in k_qkv): B[k=d][n=q], n=l15, k=quad*8+j
  bf16x8 bq[2];
  #pragma unroll
  for (int u = 0; u < 2; ++u) {
    int qn = qt*128 + w*32 + u*16 + l15;
    bq[u] = *(const bf16x8*)(qws + ((size_t)(b*S_)+qn)*256 + h*32 + quad*8);
  }
  f32x4 ao[2][2] = {};                      // [u][d-half]: D[d][q]
  float m_run[2] = {-INFINITY, -INFINITY};
  float l_run[2] = {0.f, 0.f};

  int skr = tid >> 2, skc = (tid & 3) * 8;
  int svd = tid >> 3, svn = (tid & 7) * 8;

  for (int kt = 0; kt < 12; ++kt) {
    __syncthreads();
    *(uint4*)&Ks[skr][skc] =
        *(const uint4*)(kws + ((size_t)(b*S_) + kt*64 + skr)*256 + h*32 + skc);
    *(uint4*)&Vts[svd][svn] =
        *(const uint4*)(vtws + (((size_t)(b*8+h))*32 + svd)*S_ + kt*64 + svn);
    __syncthreads();

    bf16x8 ak[4];
    #pragma unroll
    for (int t = 0; t < 4; ++t) ak[t] = *(bf16x8*)&Ks[t*16 + l15][quad*8];
    bf16x8 av[2][2];
    #pragma unroll
    for (int im = 0; im < 2; ++im)
      #pragma unroll
      for (int kc = 0; kc < 2; ++kc)
        av[im][kc] = *(bf16x8*)&Vts[im*16 + l15][kc*32 + quad*8];

    #pragma unroll
    for (int u = 0; u < 2; ++u) {
      // S^T tile: D[c = t*16 + quad*4 + r][q = l15]
      f32x4 sf[4];
      #pragma unroll
      for (int t = 0; t < 4; ++t) {
        f32x4 z = {0.f, 0.f, 0.f, 0.f};
        sf[t] = MFMA16(ak[t], bq[u], z);
      }
      // per-lane softmax over the 16 register values + 2 shfls across quads
      float m0 = sf[0][0];
      #pragma unroll
      for (int t = 0; t < 4; ++t)
        #pragma unroll
        for (int r = 0; r < 4; ++r) m0 = fmaxf(m0, sf[t][r]);
      m0 = fmaxf(m0, __shfl_xor(m0, 16, 64));
      m0 = fmaxf(m0, __shfl_xor(m0, 32, 64));
      float mnew = fmaxf(m_run[u], m0);
      float al = __expf(m_run[u] - mnew);   // exp(-inf)=0 first tile
      m_run[u] = mnew;
      float ls = 0.f;
      ushort pu[4][4];
      #pragma unroll
      for (int t = 0; t < 4; ++t)
        #pragma unroll
        for (int r = 0; r < 4; ++r) {
          float p = __expf(sf[t][r] - mnew);
          ls += p;
          pu[t][r] = f2b(p);
        }
      ls += __shfl_xor(ls, 16, 64);
      ls += __shfl_xor(ls, 32, 64);
      l_run[u] = l_run[u]*al + ls;
      // write P^T rows: Ps[q=l15][c], c = t*16+quad*4+0..3 (same-wave buffer)
      #pragma unroll
      for (int t = 0; t < 4; ++t) {
        uint2 pk;
        pk.x = (uint)pu[t][0] | ((uint)pu[t][1] << 16);
        pk.y = (uint)pu[t][2] | ((uint)pu[t][3] << 16);
        *(uint2*)&Ps[w][l15][t*16 + quad*4] = pk;
      }
      #pragma unroll
      for (int e = 0; e < 4; ++e) { ao[u][0][e] *= al; ao[u][1][e] *= al; }
      // PV: ao[u][im] += V^T * P^T, b-frag read as contiguous b128 from Ps
      #pragma unroll
      for (int kc = 0; kc < 2; ++kc) {
        bf16x8 bp = *(bf16x8*)&Ps[w][l15][kc*32 + quad*8];
        ao[u][0] = MFMA16(av[0][kc], bp, ao[u][0]);
        ao[u][1] = MFMA16(av[1][kc], bp, ao[u][1]);
      }
    }
  }
  #pragma unroll
  for (int u = 0; u < 2; ++u) {
    float linv = 1.f / l_run[u];
    int n = qt*128 + w*32 + u*16 + l15;
    ushort* orow = obuf + ((size_t)(b*S_)+n)*256 + h*32;
    #pragma unroll
    for (int im = 0; im < 2; ++im) {
      uint2 pk;
      pk.x = (uint)f2b(ao[u][im][0]*linv) | ((uint)f2b(ao[u][im][1]*linv) << 16);
      pk.y = (uint)f2b(ao[u][im][2]*linv) | ((uint)f2b(ao[u][im][3]*linv) << 16);
      *(uint2*)(orow + im*16 + quad*4) = pk;
    }
  }
}

// ---------------- proj: out += w2*(o @ attn_out_w^T + attn_out_b) ----------------
__global__ __launch_bounds__(256) void k_proj(const ushort* __restrict__ obuf, const ushort* __restrict__ wb,
                       const float* __restrict__ bias, const float* __restrict__ wgt,
                       float* __restrict__ out) {
  int dt = blockIdx.x, nt = blockIdx.y, b = blockIdx.z;
  int tid = threadIdx.x;
  int lane = tid & 63, wid = tid >> 6;
  int wm = wid >> 1, wn = wid & 1;
  int l15 = lane & 15, quad = lane >> 4;
  __shared__ __align__(16) ushort As[64][72];
  __shared__ __align__(16) ushort Ws[64][72];
  f32x4 acc[2][2] = {};
  int n0 = nt*64, d0 = dt*64;
  int sr = tid >> 2, scg = (tid & 3) * 16;
  const ushort* arow = obuf + ((size_t)(b*S_) + n0 + sr)*256;
  const ushort* wrow = wb + 458752 + (size_t)(d0+sr)*256;   // attn_out region
  for (int k0 = 0; k0 < 256; k0 += 64) {
    *(uint4*)&As[sr][scg]   = *(const uint4*)(arow + k0 + scg);
    *(uint4*)&As[sr][scg+8] = *(const uint4*)(arow + k0 + scg + 8);
    *(uint4*)&Ws[sr][scg]   = *(const uint4*)(wrow + k0 + scg);
    *(uint4*)&Ws[sr][scg+8] = *(const uint4*)(wrow + k0 + scg + 8);
    __syncthreads();
    #pragma unroll
    for (int kc = 0; kc < 2; ++kc) {
      bf16x8 a0f = *(bf16x8*)&As[wm*32 + l15][kc*32 + quad*8];
      bf16x8 a1f = *(bf16x8*)&As[wm*32 + 16 + l15][kc*32 + quad*8];
      bf16x8 b0f = *(bf16x8*)&Ws[wn*32 + l15][kc*32 + quad*8];
      bf16x8 b1f = *(bf16x8*)&Ws[wn*32 + 16 + l15][kc*32 + quad*8];
      acc[0][0] = MFMA16(a0f, b0f, acc[0][0]);
      acc[0][1] = MFMA16(a0f, b1f, acc[0][1]);
      acc[1][0] = MFMA16(a1f, b0f, acc[1][0]);
      acc[1][1] = MFMA16(a1f, b1f, acc[1][1]);
    }
    __syncthreads();
  }
  float w2v = wgt[b*4+2];
  #pragma unroll
  for (int im = 0; im < 2; ++im) {
    #pragma unroll
    for (int reg = 0; reg < 4; ++reg) {
      int n = n0 + wm*32 + im*16 + quad*4 + reg;
      float* orw = (n<N1_)? out + ((size_t)(b*N1_+n))*D_
                          : out + (size_t)IMG_OFF + ((size_t)(b*N2_+(n-N1_)))*D_;
      #pragma unroll
      for (int in = 0; in < 2; ++in) {
        int d = d0 + wn*32 + in*16 + l15;
        orw[d] += w2v*(acc[im][in][reg] + bias[d]);
      }
    }
  }
}

extern "C" void kernel_launch(void* const* d_in, const int* in_sizes, int n_in,
                              void* d_out, int out_size, void* d_ws, size_t ws_size,
                              hipStream_t stream) {
  const float* x1        = (const float*)d_in[0];
  const float* x2        = (const float*)d_in[1];
  const float* r_w1      = (const float*)d_in[2];
  const float* r_b1      = (const float*)d_in[3];
  const float* ln_g      = (const float*)d_in[4];
  const float* ln_b      = (const float*)d_in[5];
  const float* r_w2      = (const float*)d_in[6];
  const float* r_b2      = (const float*)d_in[7];
  const float* lf_w      = (const float*)d_in[8];
  const float* lf_b      = (const float*)d_in[9];
  const float* af2_w     = (const float*)d_in[10];
  const float* af2_b     = (const float*)d_in[11];
  const float* af3_w     = (const float*)d_in[12];
  const float* af3_b     = (const float*)d_in[13];
  const float* attn_in_w = (const float*)d_in[14];
  const float* attn_in_b = (const float*)d_in[15];
  const float* attn_out_w= (const float*)d_in[16];
  const float* attn_out_b= (const float*)d_in[17];
  float* out = (float*)d_out;

  // ws layout: mp[131072 f32] | w[128 f32] | qo | k | vt | zb (each B*S*256 ush) | wb[524288 ush]
  // total ~= 51.4 MB
  float* ws_mp = (float*)d_ws;
  float* ws_w  = ws_mp + 131072;
  ushort* ws_qo = (ushort*)(ws_w + 128);
  ushort* ws_k  = ws_qo + (size_t)B_*S_*256;
  ushort* ws_vt = ws_k  + (size_t)B_*S_*256;
  ushort* ws_zb = ws_vt + (size_t)B_*S_*256;
  ushort* ws_wb = ws_zb + (size_t)B_*S_*256;

  k_cvt <<<dim3(2048), 256, 0, stream>>>(x1, ws_zb, 14, 0);       // x1 -> zb rows 0..511
  k_cvt <<<dim3(1024), 256, 0, stream>>>(x2, ws_zb, 13, 131072);  // x2 -> zb rows 512..767
  k_wcvt<<<dim3(512),  256, 0, stream>>>(lf_w, af2_w, af3_w, attn_in_w, attn_out_w, ws_wb);
  k_mean<<<dim3(B_*8), 256, 0, stream>>>(x1, x2, ws_mp);
  k_head<<<dim3(B_),   256, 0, stream>>>(ws_mp, r_w1, r_b1, ln_g, ln_b, r_w2, r_b2, ws_w);
  k_lf  <<<dim3(4,12,B_), 256, 0, stream>>>(ws_zb, ws_wb, x1, x2, lf_b, ws_w, out);
  k_xout<<<dim3(4,8,B_),  256, 0, stream>>>(ws_zb, ws_wb, af2_b, af3_b, ws_w, out);
  k_qkv <<<dim3(12,12,B_),256, 0, stream>>>(ws_zb, ws_wb, attn_in_b, ws_qo, ws_k, ws_vt);
  k_attn<<<dim3(6,8,B_),  256, 0, stream>>>(ws_qo, ws_k, ws_vt, ws_qo);
  k_proj<<<dim3(4,12,B_), 256, 0, stream>>>(ws_qo, attn_out_w ? ws_wb : ws_wb, attn_out_b, ws_w, out);
}

// Round 5
// 265.609 us; speedup vs baseline: 6.0884x; 1.0756x over previous
//
#include <hip/hip_runtime.h>
#include <hip/hip_bf16.h>
#include <math.h>

// Problem: SurMoE. B=32, N1=512, N2=256, D=256, H=8, HD=32, S=768.
// Outputs: gene (32,512,256) f32 then img (32,256,256) f32, concat flat.
#define B_ 32
#define N1_ 512
#define N2_ 256
#define D_ 256
#define S_ 768
#define IMG_OFF 4194304  // 32*512*256
#define SCALE_ 0.17677669529663689f
#define QSCALE_ (0.17677669529663689f * 1.4426950408889634f)  // fold log2(e) -> use exp2

typedef __attribute__((ext_vector_type(8))) short bf16x8;
typedef __attribute__((ext_vector_type(4))) float f32x4;
#define MFMA16(a, b, c) __builtin_amdgcn_mfma_f32_16x16x32_bf16(a, b, c, 0, 0, 0)

__device__ __forceinline__ ushort f2b(float f) {
  __hip_bfloat16 h = __float2bfloat16(f);
  return __builtin_bit_cast(ushort, h);
}
__device__ __forceinline__ float eluf(float v) { return v > 0.f ? v : expm1f(v); }

// ---------------- prep: f32->bf16 z staging + deterministic partial means ----------------
__global__ __launch_bounds__(256) void k_prep(const float* __restrict__ x1,
                                              const float* __restrict__ x2,
                                              ushort* __restrict__ zb,
                                              float* __restrict__ mp) {
  int b = blockIdx.x >> 3, s = blockIdx.x & 7;
  int t = threadIdx.x;
  int c = t & 63;    // float4-column
  int rg = t >> 6;   // 0..3
  __shared__ float red[4][260];
  float4 s1 = {0.f, 0.f, 0.f, 0.f};
  for (int i = 0; i < 16; ++i) {
    int r = s*64 + rg*16 + i;
    float4 v = *(const float4*)(x1 + ((size_t)(b*N1_) + r)*D_ + c*4);
    s1.x += v.x; s1.y += v.y; s1.z += v.z; s1.w += v.w;
    uint2 pk;
    pk.x = (uint)f2b(v.x) | ((uint)f2b(v.y) << 16);
    pk.y = (uint)f2b(v.z) | ((uint)f2b(v.w) << 16);
    *(uint2*)(zb + (size_t)b*196608 + (size_t)r*256 + c*4) = pk;
  }
  red[rg][c*4+0] = s1.x; red[rg][c*4+1] = s1.y; red[rg][c*4+2] = s1.z; red[rg][c*4+3] = s1.w;
  __syncthreads();
  {
    float v = red[0][t] + red[1][t] + red[2][t] + red[3][t];
    mp[(size_t)(b*8+s)*512 + t] = v * (1.0f/512.0f);
  }
  __syncthreads();
  float4 s2 = {0.f, 0.f, 0.f, 0.f};
  for (int i = 0; i < 8; ++i) {
    int r = s*32 + rg*8 + i;
    float4 v = *(const float4*)(x2 + ((size_t)(b*N2_) + r)*D_ + c*4);
    s2.x += v.x; s2.y += v.y; s2.z += v.z; s2.w += v.w;
    uint2 pk;
    pk.x = (uint)f2b(v.x) | ((uint)f2b(v.y) << 16);
    pk.y = (uint)f2b(v.z) | ((uint)f2b(v.w) << 16);
    *(uint2*)(zb + (size_t)b*196608 + (size_t)(512 + r)*256 + c*4) = pk;
  }
  red[rg][c*4+0] = s2.x; red[rg][c*4+1] = s2.y; red[rg][c*4+2] = s2.z; red[rg][c*4+3] = s2.w;
  __syncthreads();
  {
    float v = red[0][t] + red[1][t] + red[2][t] + red[3][t];
    mp[(size_t)(b*8+s)*512 + 256 + t] = v * (1.0f/256.0f);
  }
}

// ---------------- weights -> bf16 (Wq prescaled by QSCALE) ----------------
// wb layout (elems): lf[0,64K) af2[64K,128K) af3[128K,256K) attn_in[256K,448K) attn_out[448K,512K)
__global__ __launch_bounds__(256) void k_wcvt(const float* __restrict__ lf_w,
                                              const float* __restrict__ af2_w,
                                              const float* __restrict__ af3_w,
                                              const float* __restrict__ attn_in_w,
                                              const float* __restrict__ attn_out_w,
                                              ushort* __restrict__ wb) {
  int g = blockIdx.x*256 + threadIdx.x;
  int e0 = g*4;
  const float* src; int loc; float sc = 1.f;
  if (e0 < 65536)       { src = lf_w;       loc = e0; }
  else if (e0 < 131072) { src = af2_w;      loc = e0 - 65536; }
  else if (e0 < 262144) { src = af3_w;      loc = e0 - 131072; }
  else if (e0 < 458752) { src = attn_in_w;  loc = e0 - 262144; if (loc < 65536) sc = QSCALE_; }
  else                  { src = attn_out_w; loc = e0 - 458752; }
  float4 v = *(const float4*)(src + loc);
  *(ushort4*)(wb + e0) = make_ushort4(f2b(v.x*sc), f2b(v.y*sc), f2b(v.z*sc), f2b(v.w*sc));
}

// ---------------- router head ----------------
__global__ __launch_bounds__(256) void k_head(const float* __restrict__ mp, const float* __restrict__ r_w1,
                       const float* __restrict__ r_b1, const float* __restrict__ ln_g,
                       const float* __restrict__ ln_b, const float* __restrict__ r_w2,
                       const float* __restrict__ r_b2, float* __restrict__ wout) {
  int b = blockIdx.x;
  int j = threadIdx.x;  // 256
  __shared__ float ms[512];
  __shared__ float red[256];
  float a0 = 0.f, a1 = 0.f;
  for (int s = 0; s < 8; ++s) {
    a0 += mp[(size_t)(b*8+s)*512 + j];
    a1 += mp[(size_t)(b*8+s)*512 + 256 + j];
  }
  ms[j] = a0; ms[j+256] = a1;
  __syncthreads();
  float acc = r_b1[j];
  const float* wrow = r_w1 + (size_t)j*512;
  for (int k = 0; k < 512; ++k) acc += ms[k]*wrow[k];
  red[j] = acc; __syncthreads();
  for (int off=128; off>0; off>>=1){ if (j<off) red[j]+=red[j+off]; __syncthreads(); }
  float mu = red[0] * (1.f/256.f); __syncthreads();
  float cd = acc - mu;
  red[j] = cd*cd; __syncthreads();
  for (int off=128; off>0; off>>=1){ if (j<off) red[j]+=red[j+off]; __syncthreads(); }
  float var = red[0]*(1.f/256.f); __syncthreads();
  float xn = cd * rsqrtf(var + 1e-5f) * ln_g[j] + ln_b[j];
  float h = 0.5f*xn*(1.f+erff(xn*0.70710678118654752f));
  float lg[4];
  for (int e=0;e<4;++e){
    red[j] = h * r_w2[e*256 + j]; __syncthreads();
    for (int off=128; off>0; off>>=1){ if (j<off) red[j]+=red[j+off]; __syncthreads(); }
    lg[e] = red[0] + r_b2[e]; __syncthreads();
  }
  if (j==0){
    float mx = fmaxf(fmaxf(lg[0],lg[1]),fmaxf(lg[2],lg[3]));
    float e0=expf(lg[0]-mx),e1=expf(lg[1]-mx),e2=expf(lg[2]-mx),e3=expf(lg[3]-mx);
    float s=e0+e1+e2+e3;
    wout[b*4+0]=e0/s; wout[b*4+1]=e1/s; wout[b*4+2]=e2/s; wout[b*4+3]=e3/s;
  }
}

// ---------------- qkv (128x128 tiles): q->qo[b][n][256] (prescaled), k->kh[b][h][n][32], v->vT[b][h][32][768] ----------------
__global__ __launch_bounds__(256) void k_qkv(const ushort* __restrict__ zb, const ushort* __restrict__ wb,
                      const float* __restrict__ bias,
                      ushort* __restrict__ qo, ushort* __restrict__ kh,
                      ushort* __restrict__ vt) {
  int ct = blockIdx.x, nt = blockIdx.y, b = blockIdx.z;
  int tid = threadIdx.x;
  int lane = tid & 63, wid = tid >> 6;
  int wm = wid >> 1, wn = wid & 1;
  int l15 = lane & 15, quad = lane >> 4;
  __shared__ __align__(16) ushort As[128][72];
  __shared__ __align__(16) ushort Ws[128][72];
  f32x4 acc[4][4] = {};
  int n0 = nt*128, c0 = ct*128;
  int sr = tid >> 1, sc = (tid & 1) * 32;
  const ushort* arow = zb + (size_t)b*196608 + (size_t)(n0+sr)*256;
  const ushort* wrow = wb + 262144 + (size_t)(c0+sr)*256;
  for (int k0 = 0; k0 < 256; k0 += 64) {
    #pragma unroll
    for (int i = 0; i < 4; ++i) {
      *(uint4*)&As[sr][sc + 8*i] = *(const uint4*)(arow + k0 + sc + 8*i);
      *(uint4*)&Ws[sr][sc + 8*i] = *(const uint4*)(wrow + k0 + sc + 8*i);
    }
    __syncthreads();
    #pragma unroll
    for (int kc = 0; kc < 2; ++kc) {
      bf16x8 af[4], bfr[4];
      #pragma unroll
      for (int im = 0; im < 4; ++im) af[im] = *(bf16x8*)&As[wm*64 + im*16 + l15][kc*32 + quad*8];
      #pragma unroll
      for (int in = 0; in < 4; ++in) bfr[in] = *(bf16x8*)&Ws[wn*64 + in*16 + l15][kc*32 + quad*8];
      #pragma unroll
      for (int im = 0; im < 4; ++im)
        #pragma unroll
        for (int in = 0; in < 4; ++in)
          acc[im][in] = MFMA16(af[im], bfr[in], acc[im][in]);
    }
    __syncthreads();
  }
  if (ct < 2) {          // q: prescaled, [b][n][256]
    #pragma unroll
    for (int im = 0; im < 4; ++im)
      #pragma unroll
      for (int reg = 0; reg < 4; ++reg) {
        int n = n0 + wm*64 + im*16 + quad*4 + reg;
        #pragma unroll
        for (int in = 0; in < 4; ++in) {
          int c = c0 + wn*64 + in*16 + l15;
          qo[((size_t)(b*S_)+n)*256 + c] = f2b(acc[im][in][reg] + bias[c]*QSCALE_);
        }
      }
  } else if (ct < 4) {   // k: kh[b][h][n][32]
    #pragma unroll
    for (int im = 0; im < 4; ++im)
      #pragma unroll
      for (int reg = 0; reg < 4; ++reg) {
        int n = n0 + wm*64 + im*16 + quad*4 + reg;
        #pragma unroll
        for (int in = 0; in < 4; ++in) {
          int c = c0 + wn*64 + in*16 + l15;        // global col in [256,512)
          int kc2 = c - 256; int h = kc2 >> 5, d = kc2 & 31;
          kh[(((size_t)(b*8+h))*S_ + n)*32 + d] = f2b(acc[im][in][reg] + bias[c]);
        }
      }
  } else {               // v: vT[b][h][32][768]
    #pragma unroll
    for (int im = 0; im < 4; ++im) {
      int nb = n0 + wm*64 + im*16 + quad*4;
      #pragma unroll
      for (int in = 0; in < 4; ++in) {
        int c = c0 + wn*64 + in*16 + l15;          // [512,768)
        float bs = bias[c];
        int vcol = c - 512; int h = vcol >> 5, d = vcol & 31;
        uint2 pk;
        pk.x = (uint)f2b(acc[im][in][0] + bs) | ((uint)f2b(acc[im][in][1] + bs) << 16);
        pk.y = (uint)f2b(acc[im][in][2] + bs) | ((uint)f2b(acc[im][in][3] + bs) << 16);
        *(uint2*)&vt[(((size_t)(b*8+h))*32 + d)*S_ + nb] = pk;
      }
    }
  }
}

// ---------------- flash attention, no-max softmax (safe: |s|<~6), 384 q/block ----------------
// o aliases qo: block (qh,h,b) reads exactly the q-slice it overwrites.
__global__ __launch_bounds__(256) void k_attn(const ushort* __restrict__ qo,
                                              const ushort* __restrict__ kh,
                                              const ushort* __restrict__ vt,
                                              ushort* __restrict__ obuf) {
  int qhf = blockIdx.x, h = blockIdx.y, b = blockIdx.z;
  int tid = threadIdx.x;
  int lane = tid & 63, w = tid >> 6;
  int l15 = lane & 15, quad = lane >> 4;
  __shared__ __align__(16) ushort Ks[64][40];
  __shared__ __align__(16) ushort Vts[32][72];
  __shared__ __align__(16) ushort Ps[4][16][72];

  int qbase = qhf*384 + w*96;
  bf16x8 bq[6];
  #pragma unroll
  for (int u = 0; u < 6; ++u)
    bq[u] = *(const bf16x8*)(qo + ((size_t)(b*S_) + qbase + u*16 + l15)*256 + h*32 + quad*8);

  f32x4 ao[6][2] = {};
  float lacc[6] = {};

  int skr = tid >> 2, skc = (tid & 3) * 8;
  int svd = tid >> 3, svn = (tid & 7) * 8;
  const ushort* khb = kh + ((size_t)(b*8+h))*S_*32;
  const ushort* vtb = vt + ((size_t)(b*8+h))*32*S_;

  for (int kt = 0; kt < 12; ++kt) {
    __syncthreads();
    *(uint4*)&Ks[skr][skc] = *(const uint4*)(khb + (size_t)(kt*64 + skr)*32 + skc);
    *(uint4*)&Vts[svd][svn] = *(const uint4*)(vtb + (size_t)svd*S_ + kt*64 + svn);
    __syncthreads();

    bf16x8 ak[4];
    #pragma unroll
    for (int t = 0; t < 4; ++t) ak[t] = *(bf16x8*)&Ks[t*16 + l15][quad*8];
    bf16x8 av[2][2];
    #pragma unroll
    for (int im = 0; im < 2; ++im)
      #pragma unroll
      for (int kc = 0; kc < 2; ++kc)
        av[im][kc] = *(bf16x8*)&Vts[im*16 + l15][kc*32 + quad*8];

    #pragma unroll
    for (int u = 0; u < 6; ++u) {
      f32x4 sf[4];
      #pragma unroll
      for (int t = 0; t < 4; ++t) {
        f32x4 z = {0.f, 0.f, 0.f, 0.f};
        sf[t] = MFMA16(ak[t], bq[u], z);   // S^T·log2e (scale folded into q)
      }
      #pragma unroll
      for (int t = 0; t < 4; ++t) {
        float p0 = __builtin_amdgcn_exp2f(sf[t][0]);
        float p1 = __builtin_amdgcn_exp2f(sf[t][1]);
        float p2 = __builtin_amdgcn_exp2f(sf[t][2]);
        float p3 = __builtin_amdgcn_exp2f(sf[t][3]);
        lacc[u] += (p0 + p1) + (p2 + p3);
        uint2 pk;
        pk.x = (uint)f2b(p0) | ((uint)f2b(p1) << 16);
        pk.y = (uint)f2b(p2) | ((uint)f2b(p3) << 16);
        *(uint2*)&Ps[w][l15][t*16 + quad*4] = pk;
      }
      #pragma unroll
      for (int kc = 0; kc < 2; ++kc) {
        bf16x8 bp = *(bf16x8*)&Ps[w][l15][kc*32 + quad*8];
        ao[u][0] = MFMA16(av[0][kc], bp, ao[u][0]);
        ao[u][1] = MFMA16(av[1][kc], bp, ao[u][1]);
      }
    }
  }
  #pragma unroll
  for (int u = 0; u < 6; ++u) {
    float l = lacc[u];
    l += __shfl_xor(l, 16, 64);
    l += __shfl_xor(l, 32, 64);
    float linv = 1.f / l;
    int n = qbase + u*16 + l15;
    ushort* orow = obuf + ((size_t)(b*S_)+n)*256 + h*32;
    #pragma unroll
    for (int im = 0; im < 2; ++im) {
      uint2 pk;
      pk.x = (uint)f2b(ao[u][im][0]*linv) | ((uint)f2b(ao[u][im][1]*linv) << 16);
      pk.y = (uint)f2b(ao[u][im][2]*linv) | ((uint)f2b(ao[u][im][3]*linv) << 16);
      *(uint2*)(orow + im*16 + quad*4) = pk;
    }
  }
}

// ---------------- fused output: out = w0*elu(lf) + w1*(elu(a1)+elu(a2)) + w2*(proj) + w3*z ----------------
__global__ __launch_bounds__(256) void k_out(const ushort* __restrict__ zb, const ushort* __restrict__ wb,
                      const ushort* __restrict__ ob,
                      const float* __restrict__ x1, const float* __restrict__ x2,
                      const float* __restrict__ lf_b, const float* __restrict__ af2_b,
                      const float* __restrict__ af3_b, const float* __restrict__ ao_b,
                      const float* __restrict__ wgt, float* __restrict__ out) {
  int dt = blockIdx.x, nt = blockIdx.y, b = blockIdx.z;
  int tid = threadIdx.x;
  int lane = tid & 63, wid = tid >> 6;
  int wm = wid >> 1, wn = wid & 1;
  int l15 = lane & 15, quad = lane >> 4;
  __shared__ __align__(16) ushort As[64][72];
  __shared__ __align__(16) ushort Ws[64][72];
  f32x4 a_lf[2][2] = {}, a_a1[2][2] = {}, a_a2[2][2] = {}, a_pj[2][2] = {};
  int n0 = nt*64, d0 = dt*64;
  int xr0 = ((nt < 8) ? nt : (nt - 8)) * 64;   // xout row base (x1/af3 rows)
  int sr = tid >> 2, scg = (tid & 3) * 16;

  // ---- GEMM 1: lf = zb[n] @ lf_w^T ----
  {
    const ushort* ar = zb + (size_t)b*196608 + (size_t)(n0+sr)*256;
    const ushort* wr = wb + (size_t)(d0+sr)*256;
    for (int k0 = 0; k0 < 256; k0 += 64) {
      *(uint4*)&As[sr][scg]   = *(const uint4*)(ar + k0 + scg);
      *(uint4*)&As[sr][scg+8] = *(const uint4*)(ar + k0 + scg + 8);
      *(uint4*)&Ws[sr][scg]   = *(const uint4*)(wr + k0 + scg);
      *(uint4*)&Ws[sr][scg+8] = *(const uint4*)(wr + k0 + scg + 8);
      __syncthreads();
      #pragma unroll
      for (int kc = 0; kc < 2; ++kc) {
        bf16x8 a0 = *(bf16x8*)&As[wm*32 + l15][kc*32 + quad*8];
        bf16x8 a1 = *(bf16x8*)&As[wm*32 + 16 + l15][kc*32 + quad*8];
        bf16x8 b0 = *(bf16x8*)&Ws[wn*32 + l15][kc*32 + quad*8];
        bf16x8 b1 = *(bf16x8*)&Ws[wn*32 + 16 + l15][kc*32 + quad*8];
        a_lf[0][0] = MFMA16(a0, b0, a_lf[0][0]);
        a_lf[0][1] = MFMA16(a0, b1, a_lf[0][1]);
        a_lf[1][0] = MFMA16(a1, b0, a_lf[1][0]);
        a_lf[1][1] = MFMA16(a1, b1, a_lf[1][1]);
      }
      __syncthreads();
    }
  }
  // ---- GEMM 2: a1 = x1[xr0..] @ af2_w^T ----
  {
    const ushort* ar = zb + (size_t)b*196608 + (size_t)(xr0+sr)*256;
    const ushort* wr = wb + 65536 + (size_t)(d0+sr)*256;
    for (int k0 = 0; k0 < 256; k0 += 64) {
      *(uint4*)&As[sr][scg]   = *(const uint4*)(ar + k0 + scg);
      *(uint4*)&As[sr][scg+8] = *(const uint4*)(ar + k0 + scg + 8);
      *(uint4*)&Ws[sr][scg]   = *(const uint4*)(wr + k0 + scg);
      *(uint4*)&Ws[sr][scg+8] = *(const uint4*)(wr + k0 + scg + 8);
      __syncthreads();
      #pragma unroll
      for (int kc = 0; kc < 2; ++kc) {
        bf16x8 a0 = *(bf16x8*)&As[wm*32 + l15][kc*32 + quad*8];
        bf16x8 a1 = *(bf16x8*)&As[wm*32 + 16 + l15][kc*32 + quad*8];
        bf16x8 b0 = *(bf16x8*)&Ws[wn*32 + l15][kc*32 + quad*8];
        bf16x8 b1 = *(bf16x8*)&Ws[wn*32 + 16 + l15][kc*32 + quad*8];
        a_a1[0][0] = MFMA16(a0, b0, a_a1[0][0]);
        a_a1[0][1] = MFMA16(a0, b1, a_a1[0][1]);
        a_a1[1][0] = MFMA16(a1, b0, a_a1[1][0]);
        a_a1[1][1] = MFMA16(a1, b1, a_a1[1][1]);
      }
      __syncthreads();
    }
  }
  // ---- GEMM 3: a2 = af3_w[xr0..] @ x2[b]  (B = x2^T transpose-staged) ----
  {
    const ushort* ar = wb + 131072 + (size_t)(xr0+sr)*256;
    for (int k0 = 0; k0 < 256; k0 += 64) {
      *(uint4*)&As[sr][scg]   = *(const uint4*)(ar + k0 + scg);
      *(uint4*)&As[sr][scg+8] = *(const uint4*)(ar + k0 + scg + 8);
      {
        const ushort* x2r = zb + (size_t)b*196608 + (size_t)(512 + k0 + sr)*256 + d0 + scg;
        uint4 va = *(const uint4*)x2r;
        uint4 vb = *(const uint4*)(x2r + 8);
        const ushort* ea = (const ushort*)&va;
        const ushort* eb = (const ushort*)&vb;
        #pragma unroll
        for (int i = 0; i < 8; ++i) Ws[scg + i][sr] = ea[i];
        #pragma unroll
        for (int i = 0; i < 8; ++i) Ws[scg + 8 + i][sr] = eb[i];
      }
      __syncthreads();
      #pragma unroll
      for (int kc = 0; kc < 2; ++kc) {
        bf16x8 a0 = *(bf16x8*)&As[wm*32 + l15][kc*32 + quad*8];
        bf16x8 a1 = *(bf16x8*)&As[wm*32 + 16 + l15][kc*32 + quad*8];
        bf16x8 b0 = *(bf16x8*)&Ws[wn*32 + l15][kc*32 + quad*8];
        bf16x8 b1 = *(bf16x8*)&Ws[wn*32 + 16 + l15][kc*32 + quad*8];
        a_a2[0][0] = MFMA16(a0, b0, a_a2[0][0]);
        a_a2[0][1] = MFMA16(a0, b1, a_a2[0][1]);
        a_a2[1][0] = MFMA16(a1, b0, a_a2[1][0]);
        a_a2[1][1] = MFMA16(a1, b1, a_a2[1][1]);
      }
      __syncthreads();
    }
  }
  // ---- GEMM 4: proj = o[n] @ attn_out_w^T ----
  {
    const ushort* ar = ob + ((size_t)(b*S_) + n0 + sr)*256;
    const ushort* wr = wb + 458752 + (size_t)(d0+sr)*256;
    for (int k0 = 0; k0 < 256; k0 += 64) {
      *(uint4*)&As[sr][scg]   = *(const uint4*)(ar + k0 + scg);
      *(uint4*)&As[sr][scg+8] = *(const uint4*)(ar + k0 + scg + 8);
      *(uint4*)&Ws[sr][scg]   = *(const uint4*)(wr + k0 + scg);
      *(uint4*)&Ws[sr][scg+8] = *(const uint4*)(wr + k0 + scg + 8);
      __syncthreads();
      #pragma unroll
      for (int kc = 0; kc < 2; ++kc) {
        bf16x8 a0 = *(bf16x8*)&As[wm*32 + l15][kc*32 + quad*8];
        bf16x8 a1 = *(bf16x8*)&As[wm*32 + 16 + l15][kc*32 + quad*8];
        bf16x8 b0 = *(bf16x8*)&Ws[wn*32 + l15][kc*32 + quad*8];
        bf16x8 b1 = *(bf16x8*)&Ws[wn*32 + 16 + l15][kc*32 + quad*8];
        a_pj[0][0] = MFMA16(a0, b0, a_pj[0][0]);
        a_pj[0][1] = MFMA16(a0, b1, a_pj[0][1]);
        a_pj[1][0] = MFMA16(a1, b0, a_pj[1][0]);
        a_pj[1][1] = MFMA16(a1, b1, a_pj[1][1]);
      }
      __syncthreads();
    }
  }
  // ---- epilogue ----
  float w0 = wgt[b*4+0], w1v = wgt[b*4+1], w2v = wgt[b*4+2], w3 = wgt[b*4+3];
  #pragma unroll
  for (int im = 0; im < 2; ++im) {
    #pragma unroll
    for (int reg = 0; reg < 4; ++reg) {
      int rl = wm*32 + im*16 + quad*4 + reg;   // local row
      int n = n0 + rl;
      int rx = xr0 + rl;                        // xout row (x1/af3 index)
      const float* zr; float* orw;
      if (nt < 8) { zr = x1 + ((size_t)(b*N1_) + n)*D_;      orw = out + ((size_t)(b*N1_) + n)*D_; }
      else { int j2 = n - 512; zr = x2 + ((size_t)(b*N2_) + j2)*D_;
             orw = out + (size_t)IMG_OFF + ((size_t)(b*N2_) + j2)*D_; }
      float b3 = af3_b[rx];
      #pragma unroll
      for (int in = 0; in < 2; ++in) {
        int d = d0 + wn*32 + in*16 + l15;
        float v = w0*eluf(a_lf[im][in][reg] + lf_b[d])
                + w1v*(eluf(a_a1[im][in][reg] + af2_b[d]) + eluf(a_a2[im][in][reg] + b3))
                + w2v*(a_pj[im][in][reg] + ao_b[d])
                + w3*zr[d];
        orw[d] = v;
      }
    }
  }
}

extern "C" void kernel_launch(void* const* d_in, const int* in_sizes, int n_in,
                              void* d_out, int out_size, void* d_ws, size_t ws_size,
                              hipStream_t stream) {
  const float* x1        = (const float*)d_in[0];
  const float* x2        = (const float*)d_in[1];
  const float* r_w1      = (const float*)d_in[2];
  const float* r_b1      = (const float*)d_in[3];
  const float* ln_g      = (const float*)d_in[4];
  const float* ln_b      = (const float*)d_in[5];
  const float* r_w2      = (const float*)d_in[6];
  const float* r_b2      = (const float*)d_in[7];
  const float* lf_b      = (const float*)d_in[9];
  const float* af2_b     = (const float*)d_in[11];
  const float* af3_b     = (const float*)d_in[13];
  const float* attn_in_b = (const float*)d_in[15];
  const float* attn_out_b= (const float*)d_in[17];
  float* out = (float*)d_out;

  // ws: mp[131072 f32] | w[128 f32] | zb | qo(=o) | kh | vt (each B*S*256 ush) | wb[524288 ush] ~= 52 MB
  float* ws_mp = (float*)d_ws;
  float* ws_w  = ws_mp + 131072;
  ushort* ws_zb = (ushort*)(ws_w + 128);
  ushort* ws_qo = ws_zb + (size_t)B_*S_*256;
  ushort* ws_kh = ws_qo + (size_t)B_*S_*256;
  ushort* ws_vt = ws_kh + (size_t)B_*S_*256;
  ushort* ws_wb = ws_vt + (size_t)B_*S_*256;

  k_prep<<<dim3(B_*8), 256, 0, stream>>>(x1, x2, ws_zb, ws_mp);
  k_wcvt<<<dim3(512),  256, 0, stream>>>((const float*)d_in[8], (const float*)d_in[10],
                                         (const float*)d_in[12], (const float*)d_in[14],
                                         (const float*)d_in[16], ws_wb);
  k_head<<<dim3(B_),   256, 0, stream>>>(ws_mp, r_w1, r_b1, ln_g, ln_b, r_w2, r_b2, ws_w);
  k_qkv <<<dim3(6,6,B_), 256, 0, stream>>>(ws_zb, ws_wb, attn_in_b, ws_qo, ws_kh, ws_vt);
  k_attn<<<dim3(2,8,B_), 256, 0, stream>>>(ws_qo, ws_kh, ws_vt, ws_qo);
  k_out <<<dim3(4,12,B_),256, 0, stream>>>(ws_zb, ws_wb, ws_qo, x1, x2,
                                           lf_b, af2_b, af3_b, attn_out_b, ws_w, out);
}

// Round 7
// 260.784 us; speedup vs baseline: 6.2011x; 1.0185x over previous
//
#include <hip/hip_runtime.h>
#include <hip/hip_bf16.h>
#include <math.h>

// Problem: SurMoE. B=32, N1=512, N2=256, D=256, H=8, HD=32, S=768.
// Outputs: gene (32,512,256) f32 then img (32,256,256) f32, concat flat.
#define B_ 32
#define N1_ 512
#define N2_ 256
#define D_ 256
#define S_ 768
#define IMG_OFF 4194304  // 32*512*256
#define QSCALE_ (0.17677669529663689f * 1.4426950408889634f)  // 1/sqrt(32) * log2(e)

typedef __attribute__((ext_vector_type(8))) short bf16x8;
typedef __attribute__((ext_vector_type(4))) float f32x4;
#define MFMA16(a, b, c) __builtin_amdgcn_mfma_f32_16x16x32_bf16(a, b, c, 0, 0, 0)

__device__ __forceinline__ ushort f2b(float f) {
  __hip_bfloat16 h = __float2bfloat16(f);
  return __builtin_bit_cast(ushort, h);
}
__device__ __forceinline__ uint pk2(float a, float b) {
  return (uint)f2b(a) | ((uint)f2b(b) << 16);
}
__device__ __forceinline__ float eluf(float v) { return v > 0.f ? v : expm1f(v); }

// ---------------- prep: z->bf16 staging + partial means (blocks 0..255) ----------------
// ---------------- + weights->bf16, Wq prescaled      (blocks 256..767) ----------------
// wb layout (elems): lf[0,64K) af2[64K,128K) af3[128K,256K) attn_in[256K,448K) attn_out[448K,512K)
__global__ __launch_bounds__(256) void k_prep(const float* __restrict__ x1,
                                              const float* __restrict__ x2,
                                              const float* __restrict__ lf_w,
                                              const float* __restrict__ af2_w,
                                              const float* __restrict__ af3_w,
                                              const float* __restrict__ attn_in_w,
                                              const float* __restrict__ attn_out_w,
                                              ushort* __restrict__ zb,
                                              ushort* __restrict__ wb,
                                              float* __restrict__ mp) {
  int t = threadIdx.x;
  if (blockIdx.x >= 256) {   // ---- weight conversion path ----
    int g = (blockIdx.x - 256)*256 + t;
    int e0 = g*4;
    const float* src; int loc; float sc = 1.f;
    if (e0 < 65536)       { src = lf_w;       loc = e0; }
    else if (e0 < 131072) { src = af2_w;      loc = e0 - 65536; }
    else if (e0 < 262144) { src = af3_w;      loc = e0 - 131072; }
    else if (e0 < 458752) { src = attn_in_w;  loc = e0 - 262144; if (loc < 65536) sc = QSCALE_; }
    else                  { src = attn_out_w; loc = e0 - 458752; }
    float4 v = *(const float4*)(src + loc);
    *(ushort4*)(wb + e0) = make_ushort4(f2b(v.x*sc), f2b(v.y*sc), f2b(v.z*sc), f2b(v.w*sc));
    return;
  }
  int b = blockIdx.x >> 3, s = blockIdx.x & 7;
  int c = t & 63;    // float4-column
  int rg = t >> 6;   // 0..3
  __shared__ float red[4][260];
  float4 s1 = {0.f, 0.f, 0.f, 0.f};
  for (int i = 0; i < 16; ++i) {
    int r = s*64 + rg*16 + i;
    float4 v = *(const float4*)(x1 + ((size_t)(b*N1_) + r)*D_ + c*4);
    s1.x += v.x; s1.y += v.y; s1.z += v.z; s1.w += v.w;
    uint2 pk; pk.x = pk2(v.x, v.y); pk.y = pk2(v.z, v.w);
    *(uint2*)(zb + (size_t)b*196608 + (size_t)r*256 + c*4) = pk;
  }
  red[rg][c*4+0] = s1.x; red[rg][c*4+1] = s1.y; red[rg][c*4+2] = s1.z; red[rg][c*4+3] = s1.w;
  __syncthreads();
  {
    float v = red[0][t] + red[1][t] + red[2][t] + red[3][t];
    mp[(size_t)(b*8+s)*512 + t] = v * (1.0f/512.0f);
  }
  __syncthreads();
  float4 s2 = {0.f, 0.f, 0.f, 0.f};
  for (int i = 0; i < 8; ++i) {
    int r = s*32 + rg*8 + i;
    float4 v = *(const float4*)(x2 + ((size_t)(b*N2_) + r)*D_ + c*4);
    s2.x += v.x; s2.y += v.y; s2.z += v.z; s2.w += v.w;
    uint2 pk; pk.x = pk2(v.x, v.y); pk.y = pk2(v.z, v.w);
    *(uint2*)(zb + (size_t)b*196608 + (size_t)(512 + r)*256 + c*4) = pk;
  }
  red[rg][c*4+0] = s2.x; red[rg][c*4+1] = s2.y; red[rg][c*4+2] = s2.z; red[rg][c*4+3] = s2.w;
  __syncthreads();
  {
    float v = red[0][t] + red[1][t] + red[2][t] + red[3][t];
    mp[(size_t)(b*8+s)*512 + 256 + t] = v * (1.0f/256.0f);
  }
}

// ---------------- router head ----------------
__global__ __launch_bounds__(256) void k_head(const float* __restrict__ mp, const float* __restrict__ r_w1,
                       const float* __restrict__ r_b1, const float* __restrict__ ln_g,
                       const float* __restrict__ ln_b, const float* __restrict__ r_w2,
                       const float* __restrict__ r_b2, float* __restrict__ wout) {
  int b = blockIdx.x;
  int j = threadIdx.x;  // 256
  __shared__ __align__(16) float ms[512];
  __shared__ float red[256];
  float a0 = 0.f, a1 = 0.f;
  for (int s = 0; s < 8; ++s) {
    a0 += mp[(size_t)(b*8+s)*512 + j];
    a1 += mp[(size_t)(b*8+s)*512 + 256 + j];
  }
  ms[j] = a0; ms[j+256] = a1;
  __syncthreads();
  float4 accv = {0.f, 0.f, 0.f, 0.f};
  const float4* wrow4 = (const float4*)(r_w1 + (size_t)j*512);
  const float4* ms4 = (const float4*)ms;
  for (int k = 0; k < 128; ++k) {
    float4 w = wrow4[k], m = ms4[k];
    accv.x += w.x*m.x; accv.y += w.y*m.y; accv.z += w.z*m.z; accv.w += w.w*m.w;
  }
  float acc = r_b1[j] + (accv.x + accv.y) + (accv.z + accv.w);
  red[j] = acc; __syncthreads();
  for (int off=128; off>0; off>>=1){ if (j<off) red[j]+=red[j+off]; __syncthreads(); }
  float mu = red[0] * (1.f/256.f); __syncthreads();
  float cd = acc - mu;
  red[j] = cd*cd; __syncthreads();
  for (int off=128; off>0; off>>=1){ if (j<off) red[j]+=red[j+off]; __syncthreads(); }
  float var = red[0]*(1.f/256.f); __syncthreads();
  float xn = cd * rsqrtf(var + 1e-5f) * ln_g[j] + ln_b[j];
  float h = 0.5f*xn*(1.f+erff(xn*0.70710678118654752f));
  float lg[4];
  for (int e=0;e<4;++e){
    red[j] = h * r_w2[e*256 + j]; __syncthreads();
    for (int off=128; off>0; off>>=1){ if (j<off) red[j]+=red[j+off]; __syncthreads(); }
    lg[e] = red[0] + r_b2[e]; __syncthreads();
  }
  if (j==0){
    float mx = fmaxf(fmaxf(lg[0],lg[1]),fmaxf(lg[2],lg[3]));
    float e0=expf(lg[0]-mx),e1=expf(lg[1]-mx),e2=expf(lg[2]-mx),e3=expf(lg[3]-mx);
    float s=e0+e1+e2+e3;
    wout[b*4+0]=e0/s; wout[b*4+1]=e1/s; wout[b*4+2]=e2/s; wout[b*4+3]=e3/s;
  }
}

// ---------------- qkv (128x128 tiles): q->qo[b][n][256] (prescaled), k->kh[b][h][n][32], v->vT[b][h][32][768] ----------------
__global__ __launch_bounds__(256) void k_qkv(const ushort* __restrict__ zb, const ushort* __restrict__ wb,
                      const float* __restrict__ bias,
                      ushort* __restrict__ qo, ushort* __restrict__ kh,
                      ushort* __restrict__ vt) {
  int ct = blockIdx.x, nt = blockIdx.y, b = blockIdx.z;
  int tid = threadIdx.x;
  int lane = tid & 63, wid = tid >> 6;
  int wm = wid >> 1, wn = wid & 1;
  int l15 = lane & 15, quad = lane >> 4;
  __shared__ __align__(16) ushort As[128][72];
  __shared__ __align__(16) ushort Ws[128][72];
  f32x4 acc[4][4] = {};
  int n0 = nt*128, c0 = ct*128;
  int sr = tid >> 1, sc = (tid & 1) * 32;
  const ushort* arow = zb + (size_t)b*196608 + (size_t)(n0+sr)*256;
  const ushort* wrow = wb + 262144 + (size_t)(c0+sr)*256;
  for (int k0 = 0; k0 < 256; k0 += 64) {
    #pragma unroll
    for (int i = 0; i < 4; ++i) {
      *(uint4*)&As[sr][sc + 8*i] = *(const uint4*)(arow + k0 + sc + 8*i);
      *(uint4*)&Ws[sr][sc + 8*i] = *(const uint4*)(wrow + k0 + sc + 8*i);
    }
    __syncthreads();
    #pragma unroll
    for (int kc = 0; kc < 2; ++kc) {
      bf16x8 af[4], bfr[4];
      #pragma unroll
      for (int im = 0; im < 4; ++im) af[im] = *(bf16x8*)&As[wm*64 + im*16 + l15][kc*32 + quad*8];
      #pragma unroll
      for (int in = 0; in < 4; ++in) bfr[in] = *(bf16x8*)&Ws[wn*64 + in*16 + l15][kc*32 + quad*8];
      #pragma unroll
      for (int im = 0; im < 4; ++im)
        #pragma unroll
        for (int in = 0; in < 4; ++in)
          acc[im][in] = MFMA16(af[im], bfr[in], acc[im][in]);
    }
    __syncthreads();
  }
  if (ct < 2) {          // q: prescaled, [b][n][256]
    #pragma unroll
    for (int im = 0; im < 4; ++im)
      #pragma unroll
      for (int reg = 0; reg < 4; ++reg) {
        int n = n0 + wm*64 + im*16 + quad*4 + reg;
        #pragma unroll
        for (int in = 0; in < 4; ++in) {
          int c = c0 + wn*64 + in*16 + l15;
          qo[((size_t)(b*S_)+n)*256 + c] = f2b(acc[im][in][reg] + bias[c]*QSCALE_);
        }
      }
  } else if (ct < 4) {   // k: kh[b][h][n][32]
    #pragma unroll
    for (int im = 0; im < 4; ++im)
      #pragma unroll
      for (int reg = 0; reg < 4; ++reg) {
        int n = n0 + wm*64 + im*16 + quad*4 + reg;
        #pragma unroll
        for (int in = 0; in < 4; ++in) {
          int c = c0 + wn*64 + in*16 + l15;        // global col in [256,512)
          int kc2 = c - 256; int h = kc2 >> 5, d = kc2 & 31;
          kh[(((size_t)(b*8+h))*S_ + n)*32 + d] = f2b(acc[im][in][reg] + bias[c]);
        }
      }
  } else {               // v: vT[b][h][32][768]
    #pragma unroll
    for (int im = 0; im < 4; ++im) {
      int nb = n0 + wm*64 + im*16 + quad*4;
      #pragma unroll
      for (int in = 0; in < 4; ++in) {
        int c = c0 + wn*64 + in*16 + l15;          // [512,768)
        float bs = bias[c];
        int vcol = c - 512; int h = vcol >> 5, d = vcol & 31;
        uint2 pk;
        pk.x = pk2(acc[im][in][0] + bs, acc[im][in][1] + bs);
        pk.y = pk2(acc[im][in][2] + bs, acc[im][in][3] + bs);
        *(uint2*)&vt[(((size_t)(b*8+h))*32 + d)*S_ + nb] = pk;
      }
    }
  }
}

// ---------------- flash attention, no-max softmax (|s| small), 384 q/block ----------------
// o aliases qo: block (qh,h,b) reads exactly the q-slice it overwrites.
__global__ __launch_bounds__(256) void k_attn(const ushort* __restrict__ qo,
                                              const ushort* __restrict__ kh,
                                              const ushort* __restrict__ vt,
                                              ushort* __restrict__ obuf) {
  int qhf = blockIdx.x, h = blockIdx.y, b = blockIdx.z;
  int tid = threadIdx.x;
  int lane = tid & 63, w = tid >> 6;
  int l15 = lane & 15, quad = lane >> 4;
  __shared__ __align__(16) ushort Ks[64][40];
  __shared__ __align__(16) ushort Vts[32][72];
  __shared__ __align__(16) ushort Ps[4][16][72];

  int qbase = qhf*384 + w*96;
  bf16x8 bq[6];
  #pragma unroll
  for (int u = 0; u < 6; ++u)
    bq[u] = *(const bf16x8*)(qo + ((size_t)(b*S_) + qbase + u*16 + l15)*256 + h*32 + quad*8);

  f32x4 ao[6][2] = {};
  float lacc[6] = {};

  int skr = tid >> 2, skc = (tid & 3) * 8;
  int svd = tid >> 3, svn = (tid & 7) * 8;
  const ushort* khb = kh + ((size_t)(b*8+h))*S_*32;
  const ushort* vtb = vt + ((size_t)(b*8+h))*32*S_;

  for (int kt = 0; kt < 12; ++kt) {
    __syncthreads();
    *(uint4*)&Ks[skr][skc] = *(const uint4*)(khb + (size_t)(kt*64 + skr)*32 + skc);
    *(uint4*)&Vts[svd][svn] = *(const uint4*)(vtb + (size_t)svd*S_ + kt*64 + svn);
    __syncthreads();

    bf16x8 ak[4];
    #pragma unroll
    for (int t = 0; t < 4; ++t) ak[t] = *(bf16x8*)&Ks[t*16 + l15][quad*8];
    bf16x8 av[2][2];
    #pragma unroll
    for (int im = 0; im < 2; ++im)
      #pragma unroll
      for (int kc = 0; kc < 2; ++kc)
        av[im][kc] = *(bf16x8*)&Vts[im*16 + l15][kc*32 + quad*8];

    #pragma unroll
    for (int u = 0; u < 6; ++u) {
      f32x4 sf[4];
      #pragma unroll
      for (int t = 0; t < 4; ++t) {
        f32x4 z = {0.f, 0.f, 0.f, 0.f};
        sf[t] = MFMA16(ak[t], bq[u], z);   // S^T·log2e (scale folded into q)
      }
      #pragma unroll
      for (int t = 0; t < 4; ++t) {
        float p0 = __builtin_amdgcn_exp2f(sf[t][0]);
        float p1 = __builtin_amdgcn_exp2f(sf[t][1]);
        float p2 = __builtin_amdgcn_exp2f(sf[t][2]);
        float p3 = __builtin_amdgcn_exp2f(sf[t][3]);
        lacc[u] += (p0 + p1) + (p2 + p3);
        uint2 pk;
        pk.x = pk2(p0, p1);
        pk.y = pk2(p2, p3);
        *(uint2*)&Ps[w][l15][t*16 + quad*4] = pk;
      }
      #pragma unroll
      for (int kc = 0; kc < 2; ++kc) {
        bf16x8 bp = *(bf16x8*)&Ps[w][l15][kc*32 + quad*8];
        ao[u][0] = MFMA16(av[0][kc], bp, ao[u][0]);
        ao[u][1] = MFMA16(av[1][kc], bp, ao[u][1]);
      }
    }
  }
  #pragma unroll
  for (int u = 0; u < 6; ++u) {
    float l = lacc[u];
    l += __shfl_xor(l, 16, 64);
    l += __shfl_xor(l, 32, 64);
    float linv = 1.f / l;
    int n = qbase + u*16 + l15;
    ushort* orow = obuf + ((size_t)(b*S_)+n)*256 + h*32;
    #pragma unroll
    for (int im = 0; im < 2; ++im) {
      uint2 pk;
      pk.x = pk2(ao[u][im][0]*linv, ao[u][im][1]*linv);
      pk.y = pk2(ao[u][im][2]*linv, ao[u][im][3]*linv);
      *(uint2*)(orow + im*16 + quad*4) = pk;
    }
  }
}

// ---------------- fused output: out = w0*elu(lf) + w1*(elu(a1)+elu(a2)) + w2*proj + w3*z ----------------
// Single fused k-loop over all 4 GEMMs: 8 barriers total, 32 MFMA per barrier gap.
__global__ __launch_bounds__(256) void k_out(const ushort* __restrict__ zb, const ushort* __restrict__ wb,
                      const ushort* __restrict__ ob,
                      const float* __restrict__ x1, const float* __restrict__ x2,
                      const float* __restrict__ lf_b, const float* __restrict__ af2_b,
                      const float* __restrict__ af3_b, const float* __restrict__ ao_b,
                      const float* __restrict__ wgt, float* __restrict__ out) {
  int dt = blockIdx.x, nt = blockIdx.y, b = blockIdx.z;
  int tid = threadIdx.x;
  int lane = tid & 63, wid = tid >> 6;
  int wm = wid >> 1, wn = wid & 1;
  int l15 = lane & 15, quad = lane >> 4;
  __shared__ __align__(16) ushort A1[64][72];
  __shared__ __align__(16) ushort A2[64][72];
  __shared__ __align__(16) ushort A3[64][72];
  __shared__ __align__(16) ushort A4[64][72];
  __shared__ __align__(16) ushort W1s[64][72];
  __shared__ __align__(16) ushort W2s[64][72];
  __shared__ __align__(16) ushort W3s[64][72];
  __shared__ __align__(16) ushort W4s[64][72];
  f32x4 a_lf[2][2] = {}, a_a1[2][2] = {}, a_a2[2][2] = {}, a_pj[2][2] = {};
  int n0 = nt*64, d0 = dt*64;
  int xr0 = ((nt < 8) ? nt : (nt - 8)) * 64;   // xout row base (x1/af3 rows)
  int sr = tid >> 2, scg = (tid & 3) * 16;

  const ushort* p_a1 = zb + (size_t)b*196608 + (size_t)(n0+sr)*256;   // z rows
  const ushort* p_a2 = zb + (size_t)b*196608 + (size_t)(xr0+sr)*256;  // x1 rows
  const ushort* p_a3 = wb + 131072 + (size_t)(xr0+sr)*256;            // af3 rows
  const ushort* p_a4 = ob + ((size_t)(b*S_) + n0 + sr)*256;           // o rows
  const ushort* p_w1 = wb + (size_t)(d0+sr)*256;                      // lf_w
  const ushort* p_w2 = wb + 65536 + (size_t)(d0+sr)*256;              // af2_w
  const ushort* p_w4 = wb + 458752 + (size_t)(d0+sr)*256;             // attn_out_w

  for (int k0 = 0; k0 < 256; k0 += 64) {
    *(uint4*)&A1[sr][scg]    = *(const uint4*)(p_a1 + k0 + scg);
    *(uint4*)&A1[sr][scg+8]  = *(const uint4*)(p_a1 + k0 + scg + 8);
    *(uint4*)&A2[sr][scg]    = *(const uint4*)(p_a2 + k0 + scg);
    *(uint4*)&A2[sr][scg+8]  = *(const uint4*)(p_a2 + k0 + scg + 8);
    *(uint4*)&A3[sr][scg]    = *(const uint4*)(p_a3 + k0 + scg);
    *(uint4*)&A3[sr][scg+8]  = *(const uint4*)(p_a3 + k0 + scg + 8);
    *(uint4*)&A4[sr][scg]    = *(const uint4*)(p_a4 + k0 + scg);
    *(uint4*)&A4[sr][scg+8]  = *(const uint4*)(p_a4 + k0 + scg + 8);
    *(uint4*)&W1s[sr][scg]   = *(const uint4*)(p_w1 + k0 + scg);
    *(uint4*)&W1s[sr][scg+8] = *(const uint4*)(p_w1 + k0 + scg + 8);
    *(uint4*)&W2s[sr][scg]   = *(const uint4*)(p_w2 + k0 + scg);
    *(uint4*)&W2s[sr][scg+8] = *(const uint4*)(p_w2 + k0 + scg + 8);
    *(uint4*)&W4s[sr][scg]   = *(const uint4*)(p_w4 + k0 + scg);
    *(uint4*)&W4s[sr][scg+8] = *(const uint4*)(p_w4 + k0 + scg + 8);
    {  // transpose-stage x2 tile: W3s[d-local][n2-local]
      const ushort* x2r = zb + (size_t)b*196608 + (size_t)(512 + k0 + sr)*256 + d0 + scg;
      uint4 va = *(const uint4*)x2r;
      uint4 vb = *(const uint4*)(x2r + 8);
      const ushort* ea = (const ushort*)&va;
      const ushort* eb = (const ushort*)&vb;
      #pragma unroll
      for (int i = 0; i < 8; ++i) W3s[scg + i][sr] = ea[i];
      #pragma unroll
      for (int i = 0; i < 8; ++i) W3s[scg + 8 + i][sr] = eb[i];
    }
    __syncthreads();
    #pragma unroll
    for (int kc = 0; kc < 2; ++kc) {
      int ko = kc*32 + quad*8;
      bf16x8 x0, x1r, y0, y1;
      x0 = *(bf16x8*)&A1[wm*32 + l15][ko];  x1r = *(bf16x8*)&A1[wm*32 + 16 + l15][ko];
      y0 = *(bf16x8*)&W1s[wn*32 + l15][ko]; y1  = *(bf16x8*)&W1s[wn*32 + 16 + l15][ko];
      a_lf[0][0] = MFMA16(x0, y0, a_lf[0][0]);  a_lf[0][1] = MFMA16(x0, y1, a_lf[0][1]);
      a_lf[1][0] = MFMA16(x1r, y0, a_lf[1][0]); a_lf[1][1] = MFMA16(x1r, y1, a_lf[1][1]);
      x0 = *(bf16x8*)&A2[wm*32 + l15][ko];  x1r = *(bf16x8*)&A2[wm*32 + 16 + l15][ko];
      y0 = *(bf16x8*)&W2s[wn*32 + l15][ko]; y1  = *(bf16x8*)&W2s[wn*32 + 16 + l15][ko];
      a_a1[0][0] = MFMA16(x0, y0, a_a1[0][0]);  a_a1[0][1] = MFMA16(x0, y1, a_a1[0][1]);
      a_a1[1][0] = MFMA16(x1r, y0, a_a1[1][0]); a_a1[1][1] = MFMA16(x1r, y1, a_a1[1][1]);
      x0 = *(bf16x8*)&A3[wm*32 + l15][ko];  x1r = *(bf16x8*)&A3[wm*32 + 16 + l15][ko];
      y0 = *(bf16x8*)&W3s[wn*32 + l15][ko]; y1  = *(bf16x8*)&W3s[wn*32 + 16 + l15][ko];
      a_a2[0][0] = MFMA16(x0, y0, a_a2[0][0]);  a_a2[0][1] = MFMA16(x0, y1, a_a2[0][1]);
      a_a2[1][0] = MFMA16(x1r, y0, a_a2[1][0]); a_a2[1][1] = MFMA16(x1r, y1, a_a2[1][1]);
      x0 = *(bf16x8*)&A4[wm*32 + l15][ko];  x1r = *(bf16x8*)&A4[wm*32 + 16 + l15][ko];
      y0 = *(bf16x8*)&W4s[wn*32 + l15][ko]; y1  = *(bf16x8*)&W4s[wn*32 + 16 + l15][ko];
      a_pj[0][0] = MFMA16(x0, y0, a_pj[0][0]);  a_pj[0][1] = MFMA16(x0, y1, a_pj[0][1]);
      a_pj[1][0] = MFMA16(x1r, y0, a_pj[1][0]); a_pj[1][1] = MFMA16(x1r, y1, a_pj[1][1]);
    }
    __syncthreads();
  }
  // ---- epilogue ----
  float w0 = wgt[b*4+0], w1v = wgt[b*4+1], w2v = wgt[b*4+2], w3 = wgt[b*4+3];
  #pragma unroll
  for (int im = 0; im < 2; ++im) {
    #pragma unroll
    for (int reg = 0; reg < 4; ++reg) {
      int rl = wm*32 + im*16 + quad*4 + reg;   // local row
      int n = n0 + rl;
      int rx = xr0 + rl;                        // xout row (x1/af3 index)
      const float* zr; float* orw;
      if (nt < 8) { zr = x1 + ((size_t)(b*N1_) + n)*D_;      orw = out + ((size_t)(b*N1_) + n)*D_; }
      else { int j2 = n - 512; zr = x2 + ((size_t)(b*N2_) + j2)*D_;
             orw = out + (size_t)IMG_OFF + ((size_t)(b*N2_) + j2)*D_; }
      float b3 = af3_b[rx];
      #pragma unroll
      for (int in = 0; in < 2; ++in) {
        int d = d0 + wn*32 + in*16 + l15;
        float v = w0*eluf(a_lf[im][in][reg] + lf_b[d])
                + w1v*(eluf(a_a1[im][in][reg] + af2_b[d]) + eluf(a_a2[im][in][reg] + b3))
                + w2v*(a_pj[im][in][reg] + ao_b[d])
                + w3*zr[d];
        orw[d] = v;
      }
    }
  }
}

extern "C" void kernel_launch(void* const* d_in, const int* in_sizes, int n_in,
                              void* d_out, int out_size, void* d_ws, size_t ws_size,
                              hipStream_t stream) {
  const float* x1        = (const float*)d_in[0];
  const float* x2        = (const float*)d_in[1];
  const float* r_w1      = (const float*)d_in[2];
  const float* r_b1      = (const float*)d_in[3];
  const float* ln_g      = (const float*)d_in[4];
  const float* ln_b      = (const float*)d_in[5];
  const float* r_w2      = (const float*)d_in[6];
  const float* r_b2      = (const float*)d_in[7];
  const float* lf_b      = (const float*)d_in[9];
  const float* af2_b     = (const float*)d_in[11];
  const float* af3_b     = (const float*)d_in[13];
  const float* attn_in_b = (const float*)d_in[15];
  const float* attn_out_b= (const float*)d_in[17];
  float* out = (float*)d_out;

  // ws: mp[131072 f32] | w[128 f32] | zb | qo(=o) | kh | vt (each B*S*256 ush) | wb[524288 ush] ~= 52 MB
  float* ws_mp = (float*)d_ws;
  float* ws_w  = ws_mp + 131072;
  ushort* ws_zb = (ushort*)(ws_w + 128);
  ushort* ws_qo = ws_zb + (size_t)B_*S_*256;
  ushort* ws_kh = ws_qo + (size_t)B_*S_*256;
  ushort* ws_vt = ws_kh + (size_t)B_*S_*256;
  ushort* ws_wb = ws_vt + (size_t)B_*S_*256;

  k_prep<<<dim3(768), 256, 0, stream>>>(x1, x2, (const float*)d_in[8], (const float*)d_in[10],
                                        (const float*)d_in[12], (const float*)d_in[14],
                                        (const float*)d_in[16], ws_zb, ws_wb, ws_mp);
  k_head<<<dim3(B_),   256, 0, stream>>>(ws_mp, r_w1, r_b1, ln_g, ln_b, r_w2, r_b2, ws_w);
  k_qkv <<<dim3(6,6,B_), 256, 0, stream>>>(ws_zb, ws_wb, attn_in_b, ws_qo, ws_kh, ws_vt);
  k_attn<<<dim3(2,8,B_), 256, 0, stream>>>(ws_qo, ws_kh, ws_vt, ws_qo);
  k_out <<<dim3(4,12,B_),256, 0, stream>>>(ws_zb, ws_wb, ws_qo, x1, x2,
                                           lf_b, af2_b, af3_b, attn_out_b, ws_w, out);
}

// Round 8
// 253.050 us; speedup vs baseline: 6.3906x; 1.0306x over previous
//
#include <hip/hip_runtime.h>
#include <hip/hip_bf16.h>
#include <math.h>

// Problem: SurMoE. B=32, N1=512, N2=256, D=256, H=8, HD=32, S=768.
// Outputs: gene (32,512,256) f32 then img (32,256,256) f32, concat flat.
#define B_ 32
#define N1_ 512
#define N2_ 256
#define D_ 256
#define S_ 768
#define IMG_OFF 4194304  // 32*512*256
#define QSCALE_ (0.17677669529663689f * 1.4426950408889634f)  // 1/sqrt(32) * log2(e)

typedef __attribute__((ext_vector_type(8))) short bf16x8;
typedef __attribute__((ext_vector_type(4))) float f32x4;
#define MFMA16(a, b, c) __builtin_amdgcn_mfma_f32_16x16x32_bf16(a, b, c, 0, 0, 0)

__device__ __forceinline__ ushort f2b(float f) {
  __hip_bfloat16 h = __float2bfloat16(f);
  return __builtin_bit_cast(ushort, h);
}
__device__ __forceinline__ uint pk2(float a, float b) {
  return (uint)f2b(a) | ((uint)f2b(b) << 16);
}
__device__ __forceinline__ float b2f(ushort u) {
  return __builtin_bit_cast(float, ((uint)u) << 16);
}
__device__ __forceinline__ float eluf(float v) { return v > 0.f ? v : expm1f(v); }

// ---------------- prep: z->bf16 staging + partial means + x2T (blocks 0..255) ----------------
// ---------------- + weights->bf16, Wq prescaled              (blocks 256..767) ----------------
// wb layout (elems): lf[0,64K) af2[64K,128K) af3[128K,256K) attn_in[256K,448K) attn_out[448K,512K)
__global__ __launch_bounds__(256) void k_prep(const float* __restrict__ x1,
                                              const float* __restrict__ x2,
                                              const float* __restrict__ lf_w,
                                              const float* __restrict__ af2_w,
                                              const float* __restrict__ af3_w,
                                              const float* __restrict__ attn_in_w,
                                              const float* __restrict__ attn_out_w,
                                              ushort* __restrict__ zb,
                                              ushort* __restrict__ wb,
                                              ushort* __restrict__ x2t,
                                              float* __restrict__ mp) {
  int t = threadIdx.x;
  if (blockIdx.x >= 256) {   // ---- weight conversion path ----
    int g = (blockIdx.x - 256)*256 + t;
    int e0 = g*4;
    const float* src; int loc; float sc = 1.f;
    if (e0 < 65536)       { src = lf_w;       loc = e0; }
    else if (e0 < 131072) { src = af2_w;      loc = e0 - 65536; }
    else if (e0 < 262144) { src = af3_w;      loc = e0 - 131072; }
    else if (e0 < 458752) { src = attn_in_w;  loc = e0 - 262144; if (loc < 65536) sc = QSCALE_; }
    else                  { src = attn_out_w; loc = e0 - 458752; }
    float4 v = *(const float4*)(src + loc);
    *(ushort4*)(wb + e0) = make_ushort4(f2b(v.x*sc), f2b(v.y*sc), f2b(v.z*sc), f2b(v.w*sc));
    return;
  }
  int b = blockIdx.x >> 3, s = blockIdx.x & 7;
  int c = t & 63;    // float4-column
  int rg = t >> 6;   // 0..3
  __shared__ float red[4][260];
  __shared__ ushort xt[32][266];
  float4 s1 = {0.f, 0.f, 0.f, 0.f};
  for (int i = 0; i < 16; ++i) {
    int r = s*64 + rg*16 + i;
    float4 v = *(const float4*)(x1 + ((size_t)(b*N1_) + r)*D_ + c*4);
    s1.x += v.x; s1.y += v.y; s1.z += v.z; s1.w += v.w;
    uint2 pk; pk.x = pk2(v.x, v.y); pk.y = pk2(v.z, v.w);
    *(uint2*)(zb + (size_t)b*196608 + (size_t)r*256 + c*4) = pk;
  }
  red[rg][c*4+0] = s1.x; red[rg][c*4+1] = s1.y; red[rg][c*4+2] = s1.z; red[rg][c*4+3] = s1.w;
  __syncthreads();
  {
    float v = red[0][t] + red[1][t] + red[2][t] + red[3][t];
    mp[(size_t)(b*8+s)*512 + t] = v * (1.0f/512.0f);
  }
  __syncthreads();
  float4 s2 = {0.f, 0.f, 0.f, 0.f};
  for (int i = 0; i < 8; ++i) {
    int rl = rg*8 + i;
    int r = s*32 + rl;
    float4 v = *(const float4*)(x2 + ((size_t)(b*N2_) + r)*D_ + c*4);
    s2.x += v.x; s2.y += v.y; s2.z += v.z; s2.w += v.w;
    ushort b0 = f2b(v.x), b1 = f2b(v.y), b2 = f2b(v.z), b3 = f2b(v.w);
    uint2 pk; pk.x = (uint)b0 | ((uint)b1 << 16); pk.y = (uint)b2 | ((uint)b3 << 16);
    *(uint2*)(zb + (size_t)b*196608 + (size_t)(512 + r)*256 + c*4) = pk;
    xt[rl][c*4+0] = b0; xt[rl][c*4+1] = b1; xt[rl][c*4+2] = b2; xt[rl][c*4+3] = b3;
  }
  red[rg][c*4+0] = s2.x; red[rg][c*4+1] = s2.y; red[rg][c*4+2] = s2.z; red[rg][c*4+3] = s2.w;
  __syncthreads();
  {
    float v = red[0][t] + red[1][t] + red[2][t] + red[3][t];
    mp[(size_t)(b*8+s)*512 + 256 + t] = v * (1.0f/256.0f);
  }
  // x2T: thread t owns d=t, writes n2 = s*32..s*32+31 (32 ushorts = 4 uint4)
  ushort* dst = x2t + (size_t)b*65536 + (size_t)t*256 + s*32;
  #pragma unroll
  for (int g = 0; g < 4; ++g) {
    uint4 w;
    w.x = (uint)xt[g*8+0][t] | ((uint)xt[g*8+1][t] << 16);
    w.y = (uint)xt[g*8+2][t] | ((uint)xt[g*8+3][t] << 16);
    w.z = (uint)xt[g*8+4][t] | ((uint)xt[g*8+5][t] << 16);
    w.w = (uint)xt[g*8+6][t] | ((uint)xt[g*8+7][t] << 16);
    *(uint4*)(dst + g*8) = w;
  }
}

// ---------------- router head ----------------
__global__ __launch_bounds__(256) void k_head(const float* __restrict__ mp, const float* __restrict__ r_w1,
                       const float* __restrict__ r_b1, const float* __restrict__ ln_g,
                       const float* __restrict__ ln_b, const float* __restrict__ r_w2,
                       const float* __restrict__ r_b2, float* __restrict__ wout) {
  int b = blockIdx.x;
  int j = threadIdx.x;  // 256
  __shared__ __align__(16) float ms[512];
  __shared__ float red[256];
  float a0 = 0.f, a1 = 0.f;
  for (int s = 0; s < 8; ++s) {
    a0 += mp[(size_t)(b*8+s)*512 + j];
    a1 += mp[(size_t)(b*8+s)*512 + 256 + j];
  }
  ms[j] = a0; ms[j+256] = a1;
  __syncthreads();
  float4 accv = {0.f, 0.f, 0.f, 0.f};
  const float4* wrow4 = (const float4*)(r_w1 + (size_t)j*512);
  const float4* ms4 = (const float4*)ms;
  for (int k = 0; k < 128; ++k) {
    float4 w = wrow4[k], m = ms4[k];
    accv.x += w.x*m.x; accv.y += w.y*m.y; accv.z += w.z*m.z; accv.w += w.w*m.w;
  }
  float acc = r_b1[j] + (accv.x + accv.y) + (accv.z + accv.w);
  red[j] = acc; __syncthreads();
  for (int off=128; off>0; off>>=1){ if (j<off) red[j]+=red[j+off]; __syncthreads(); }
  float mu = red[0] * (1.f/256.f); __syncthreads();
  float cd = acc - mu;
  red[j] = cd*cd; __syncthreads();
  for (int off=128; off>0; off>>=1){ if (j<off) red[j]+=red[j+off]; __syncthreads(); }
  float var = red[0]*(1.f/256.f); __syncthreads();
  float xn = cd * rsqrtf(var + 1e-5f) * ln_g[j] + ln_b[j];
  float h = 0.5f*xn*(1.f+erff(xn*0.70710678118654752f));
  float lg[4];
  for (int e=0;e<4;++e){
    red[j] = h * r_w2[e*256 + j]; __syncthreads();
    for (int off=128; off>0; off>>=1){ if (j<off) red[j]+=red[j+off]; __syncthreads(); }
    lg[e] = red[0] + r_b2[e]; __syncthreads();
  }
  if (j==0){
    float mx = fmaxf(fmaxf(lg[0],lg[1]),fmaxf(lg[2],lg[3]));
    float e0=expf(lg[0]-mx),e1=expf(lg[1]-mx),e2=expf(lg[2]-mx),e3=expf(lg[3]-mx);
    float s=e0+e1+e2+e3;
    wout[b*4+0]=e0/s; wout[b*4+1]=e1/s; wout[b*4+2]=e2/s; wout[b*4+3]=e3/s;
  }
}

// ---------------- qkv (128x128 tiles): q->qo[b][n][256] (prescaled), k->kh[b][h][n][32], v->vT[b][h][32][768] ----------------
__global__ __launch_bounds__(256) void k_qkv(const ushort* __restrict__ zb, const ushort* __restrict__ wb,
                      const float* __restrict__ bias,
                      ushort* __restrict__ qo, ushort* __restrict__ kh,
                      ushort* __restrict__ vt) {
  int ct = blockIdx.x, nt = blockIdx.y, b = blockIdx.z;
  int tid = threadIdx.x;
  int lane = tid & 63, wid = tid >> 6;
  int wm = wid >> 1, wn = wid & 1;
  int l15 = lane & 15, quad = lane >> 4;
  __shared__ __align__(16) ushort As[128][72];
  __shared__ __align__(16) ushort Ws[128][72];
  f32x4 acc[4][4] = {};
  int n0 = nt*128, c0 = ct*128;
  int sr = tid >> 1, sc = (tid & 1) * 32;
  const ushort* arow = zb + (size_t)b*196608 + (size_t)(n0+sr)*256;
  const ushort* wrow = wb + 262144 + (size_t)(c0+sr)*256;
  for (int k0 = 0; k0 < 256; k0 += 64) {
    #pragma unroll
    for (int i = 0; i < 4; ++i) {
      *(uint4*)&As[sr][sc + 8*i] = *(const uint4*)(arow + k0 + sc + 8*i);
      *(uint4*)&Ws[sr][sc + 8*i] = *(const uint4*)(wrow + k0 + sc + 8*i);
    }
    __syncthreads();
    #pragma unroll
    for (int kc = 0; kc < 2; ++kc) {
      bf16x8 af[4], bfr[4];
      #pragma unroll
      for (int im = 0; im < 4; ++im) af[im] = *(bf16x8*)&As[wm*64 + im*16 + l15][kc*32 + quad*8];
      #pragma unroll
      for (int in = 0; in < 4; ++in) bfr[in] = *(bf16x8*)&Ws[wn*64 + in*16 + l15][kc*32 + quad*8];
      #pragma unroll
      for (int im = 0; im < 4; ++im)
        #pragma unroll
        for (int in = 0; in < 4; ++in)
          acc[im][in] = MFMA16(af[im], bfr[in], acc[im][in]);
    }
    __syncthreads();
  }
  if (ct < 2) {          // q: prescaled, [b][n][256]
    #pragma unroll
    for (int im = 0; im < 4; ++im)
      #pragma unroll
      for (int reg = 0; reg < 4; ++reg) {
        int n = n0 + wm*64 + im*16 + quad*4 + reg;
        #pragma unroll
        for (int in = 0; in < 4; ++in) {
          int c = c0 + wn*64 + in*16 + l15;
          qo[((size_t)(b*S_)+n)*256 + c] = f2b(acc[im][in][reg] + bias[c]*QSCALE_);
        }
      }
  } else if (ct < 4) {   // k: kh[b][h][n][32]
    #pragma unroll
    for (int im = 0; im < 4; ++im)
      #pragma unroll
      for (int reg = 0; reg < 4; ++reg) {
        int n = n0 + wm*64 + im*16 + quad*4 + reg;
        #pragma unroll
        for (int in = 0; in < 4; ++in) {
          int c = c0 + wn*64 + in*16 + l15;        // global col in [256,512)
          int kc2 = c - 256; int h = kc2 >> 5, d = kc2 & 31;
          kh[(((size_t)(b*8+h))*S_ + n)*32 + d] = f2b(acc[im][in][reg] + bias[c]);
        }
      }
  } else {               // v: vT[b][h][32][768]
    #pragma unroll
    for (int im = 0; im < 4; ++im) {
      int nb = n0 + wm*64 + im*16 + quad*4;
      #pragma unroll
      for (int in = 0; in < 4; ++in) {
        int c = c0 + wn*64 + in*16 + l15;          // [512,768)
        float bs = bias[c];
        int vcol = c - 512; int h = vcol >> 5, d = vcol & 31;
        uint2 pk;
        pk.x = pk2(acc[im][in][0] + bs, acc[im][in][1] + bs);
        pk.y = pk2(acc[im][in][2] + bs, acc[im][in][3] + bs);
        *(uint2*)&vt[(((size_t)(b*8+h))*32 + d)*S_ + nb] = pk;
      }
    }
  }
}

// ---------------- flash attention, no-max softmax (|s| small), 384 q/block ----------------
// o aliases qo: block (qh,h,b) reads exactly the q-slice it overwrites.
__global__ __launch_bounds__(256) void k_attn(const ushort* __restrict__ qo,
                                              const ushort* __restrict__ kh,
                                              const ushort* __restrict__ vt,
                                              ushort* __restrict__ obuf) {
  int qhf = blockIdx.x, h = blockIdx.y, b = blockIdx.z;
  int tid = threadIdx.x;
  int lane = tid & 63, w = tid >> 6;
  int l15 = lane & 15, quad = lane >> 4;
  __shared__ __align__(16) ushort Ks[64][40];
  __shared__ __align__(16) ushort Vts[32][72];
  __shared__ __align__(16) ushort Ps[4][16][72];

  int qbase = qhf*384 + w*96;
  bf16x8 bq[6];
  #pragma unroll
  for (int u = 0; u < 6; ++u)
    bq[u] = *(const bf16x8*)(qo + ((size_t)(b*S_) + qbase + u*16 + l15)*256 + h*32 + quad*8);

  f32x4 ao[6][2] = {};
  float lacc[6] = {};

  int skr = tid >> 2, skc = (tid & 3) * 8;
  int svd = tid >> 3, svn = (tid & 7) * 8;
  const ushort* khb = kh + ((size_t)(b*8+h))*S_*32;
  const ushort* vtb = vt + ((size_t)(b*8+h))*32*S_;

  for (int kt = 0; kt < 12; ++kt) {
    __syncthreads();
    *(uint4*)&Ks[skr][skc] = *(const uint4*)(khb + (size_t)(kt*64 + skr)*32 + skc);
    *(uint4*)&Vts[svd][svn] = *(const uint4*)(vtb + (size_t)svd*S_ + kt*64 + svn);
    __syncthreads();

    bf16x8 ak[4];
    #pragma unroll
    for (int t = 0; t < 4; ++t) ak[t] = *(bf16x8*)&Ks[t*16 + l15][quad*8];
    bf16x8 av[2][2];
    #pragma unroll
    for (int im = 0; im < 2; ++im)
      #pragma unroll
      for (int kc = 0; kc < 2; ++kc)
        av[im][kc] = *(bf16x8*)&Vts[im*16 + l15][kc*32 + quad*8];

    #pragma unroll
    for (int u = 0; u < 6; ++u) {
      f32x4 sf[4];
      #pragma unroll
      for (int t = 0; t < 4; ++t) {
        f32x4 z = {0.f, 0.f, 0.f, 0.f};
        sf[t] = MFMA16(ak[t], bq[u], z);   // S^T·log2e (scale folded into q)
      }
      #pragma unroll
      for (int t = 0; t < 4; ++t) {
        float p0 = __builtin_amdgcn_exp2f(sf[t][0]);
        float p1 = __builtin_amdgcn_exp2f(sf[t][1]);
        float p2 = __builtin_amdgcn_exp2f(sf[t][2]);
        float p3 = __builtin_amdgcn_exp2f(sf[t][3]);
        lacc[u] += (p0 + p1) + (p2 + p3);
        uint2 pk;
        pk.x = pk2(p0, p1);
        pk.y = pk2(p2, p3);
        *(uint2*)&Ps[w][l15][t*16 + quad*4] = pk;
      }
      #pragma unroll
      for (int kc = 0; kc < 2; ++kc) {
        bf16x8 bp = *(bf16x8*)&Ps[w][l15][kc*32 + quad*8];
        ao[u][0] = MFMA16(av[0][kc], bp, ao[u][0]);
        ao[u][1] = MFMA16(av[1][kc], bp, ao[u][1]);
      }
    }
  }
  #pragma unroll
  for (int u = 0; u < 6; ++u) {
    float l = lacc[u];
    l += __shfl_xor(l, 16, 64);
    l += __shfl_xor(l, 32, 64);
    float linv = 1.f / l;
    int n = qbase + u*16 + l15;
    ushort* orow = obuf + ((size_t)(b*S_)+n)*256 + h*32;
    #pragma unroll
    for (int im = 0; im < 2; ++im) {
      uint2 pk;
      pk.x = pk2(ao[u][im][0]*linv, ao[u][im][1]*linv);
      pk.y = pk2(ao[u][im][2]*linv, ao[u][im][3]*linv);
      *(uint2*)(orow + im*16 + quad*4) = pk;
    }
  }
}

// ---------------- fused output: out = w0*elu(lf) + w1*(elu(a1)+elu(a2)) + w2*proj + w3*z ----------------
// Single fused k-loop, K=32 chunks, 8 uniform vectorized stagings (x2T precomputed),
// 36.9 KB LDS -> 4 blocks/CU.
__global__ __launch_bounds__(256) void k_out(const ushort* __restrict__ zb, const ushort* __restrict__ wb,
                      const ushort* __restrict__ ob, const ushort* __restrict__ x2t,
                      const float* __restrict__ lf_b, const float* __restrict__ af2_b,
                      const float* __restrict__ af3_b, const float* __restrict__ ao_b,
                      const float* __restrict__ wgt, float* __restrict__ out) {
  int dt = blockIdx.x, nt = blockIdx.y, b = blockIdx.z;
  int tid = threadIdx.x;
  int lane = tid & 63, wid = tid >> 6;
  int wm = wid >> 1, wn = wid & 1;
  int l15 = lane & 15, quad = lane >> 4;
  __shared__ __align__(16) ushort A1[64][36];
  __shared__ __align__(16) ushort A2[64][36];
  __shared__ __align__(16) ushort A3[64][36];
  __shared__ __align__(16) ushort A4[64][36];
  __shared__ __align__(16) ushort W1s[64][36];
  __shared__ __align__(16) ushort W2s[64][36];
  __shared__ __align__(16) ushort W3s[64][36];
  __shared__ __align__(16) ushort W4s[64][36];
  f32x4 a_lf[2][2] = {}, a_a1[2][2] = {}, a_a2[2][2] = {}, a_pj[2][2] = {};
  int n0 = nt*64, d0 = dt*64;
  int xr0 = ((nt < 8) ? nt : (nt - 8)) * 64;   // xout row base (x1/af3 rows)
  int sr = tid >> 2, sc4 = (tid & 3) * 8;

  const ushort* p_a1 = zb + (size_t)b*196608 + (size_t)(n0+sr)*256 + sc4;   // z rows
  const ushort* p_a2 = zb + (size_t)b*196608 + (size_t)(xr0+sr)*256 + sc4;  // x1 rows
  const ushort* p_a3 = wb + 131072 + (size_t)(xr0+sr)*256 + sc4;            // af3 rows
  const ushort* p_a4 = ob + ((size_t)(b*S_) + n0 + sr)*256 + sc4;           // o rows
  const ushort* p_w1 = wb + (size_t)(d0+sr)*256 + sc4;                      // lf_w
  const ushort* p_w2 = wb + 65536 + (size_t)(d0+sr)*256 + sc4;              // af2_w
  const ushort* p_w3 = x2t + (size_t)b*65536 + (size_t)(d0+sr)*256 + sc4;   // x2^T rows (d)
  const ushort* p_w4 = wb + 458752 + (size_t)(d0+sr)*256 + sc4;             // attn_out_w

  for (int k0 = 0; k0 < 256; k0 += 32) {
    *(uint4*)&A1[sr][sc4]  = *(const uint4*)(p_a1 + k0);
    *(uint4*)&A2[sr][sc4]  = *(const uint4*)(p_a2 + k0);
    *(uint4*)&A3[sr][sc4]  = *(const uint4*)(p_a3 + k0);
    *(uint4*)&A4[sr][sc4]  = *(const uint4*)(p_a4 + k0);
    *(uint4*)&W1s[sr][sc4] = *(const uint4*)(p_w1 + k0);
    *(uint4*)&W2s[sr][sc4] = *(const uint4*)(p_w2 + k0);
    *(uint4*)&W3s[sr][sc4] = *(const uint4*)(p_w3 + k0);
    *(uint4*)&W4s[sr][sc4] = *(const uint4*)(p_w4 + k0);
    __syncthreads();
    {
      int ko = quad*8;
      bf16x8 x0, x1r, y0, y1;
      x0 = *(bf16x8*)&A1[wm*32 + l15][ko];  x1r = *(bf16x8*)&A1[wm*32 + 16 + l15][ko];
      y0 = *(bf16x8*)&W1s[wn*32 + l15][ko]; y1  = *(bf16x8*)&W1s[wn*32 + 16 + l15][ko];
      a_lf[0][0] = MFMA16(x0, y0, a_lf[0][0]);  a_lf[0][1] = MFMA16(x0, y1, a_lf[0][1]);
      a_lf[1][0] = MFMA16(x1r, y0, a_lf[1][0]); a_lf[1][1] = MFMA16(x1r, y1, a_lf[1][1]);
      x0 = *(bf16x8*)&A2[wm*32 + l15][ko];  x1r = *(bf16x8*)&A2[wm*32 + 16 + l15][ko];
      y0 = *(bf16x8*)&W2s[wn*32 + l15][ko]; y1  = *(bf16x8*)&W2s[wn*32 + 16 + l15][ko];
      a_a1[0][0] = MFMA16(x0, y0, a_a1[0][0]);  a_a1[0][1] = MFMA16(x0, y1, a_a1[0][1]);
      a_a1[1][0] = MFMA16(x1r, y0, a_a1[1][0]); a_a1[1][1] = MFMA16(x1r, y1, a_a1[1][1]);
      x0 = *(bf16x8*)&A3[wm*32 + l15][ko];  x1r = *(bf16x8*)&A3[wm*32 + 16 + l15][ko];
      y0 = *(bf16x8*)&W3s[wn*32 + l15][ko]; y1  = *(bf16x8*)&W3s[wn*32 + 16 + l15][ko];
      a_a2[0][0] = MFMA16(x0, y0, a_a2[0][0]);  a_a2[0][1] = MFMA16(x0, y1, a_a2[0][1]);
      a_a2[1][0] = MFMA16(x1r, y0, a_a2[1][0]); a_a2[1][1] = MFMA16(x1r, y1, a_a2[1][1]);
      x0 = *(bf16x8*)&A4[wm*32 + l15][ko];  x1r = *(bf16x8*)&A4[wm*32 + 16 + l15][ko];
      y0 = *(bf16x8*)&W4s[wn*32 + l15][ko]; y1  = *(bf16x8*)&W4s[wn*32 + 16 + l15][ko];
      a_pj[0][0] = MFMA16(x0, y0, a_pj[0][0]);  a_pj[0][1] = MFMA16(x0, y1, a_pj[0][1]);
      a_pj[1][0] = MFMA16(x1r, y0, a_pj[1][0]); a_pj[1][1] = MFMA16(x1r, y1, a_pj[1][1]);
    }
    __syncthreads();
  }
  // ---- epilogue (z-term from bf16 zb; rows L2-hot from A1 staging) ----
  float w0 = wgt[b*4+0], w1v = wgt[b*4+1], w2v = wgt[b*4+2], w3 = wgt[b*4+3];
  #pragma unroll
  for (int im = 0; im < 2; ++im) {
    #pragma unroll
    for (int reg = 0; reg < 4; ++reg) {
      int rl = wm*32 + im*16 + quad*4 + reg;   // local row
      int n = n0 + rl;
      int rx = xr0 + rl;                        // xout row (x1/af3 index)
      const ushort* zr = zb + (size_t)b*196608 + (size_t)n*256;
      float* orw = (nt < 8) ? out + ((size_t)(b*N1_) + n)*D_
                            : out + (size_t)IMG_OFF + ((size_t)(b*N2_) + (n - 512))*D_;
      float b3 = af3_b[rx];
      #pragma unroll
      for (int in = 0; in < 2; ++in) {
        int d = d0 + wn*32 + in*16 + l15;
        float v = w0*eluf(a_lf[im][in][reg] + lf_b[d])
                + w1v*(eluf(a_a1[im][in][reg] + af2_b[d]) + eluf(a_a2[im][in][reg] + b3))
                + w2v*(a_pj[im][in][reg] + ao_b[d])
                + w3*b2f(zr[d]);
        orw[d] = v;
      }
    }
  }
}

extern "C" void kernel_launch(void* const* d_in, const int* in_sizes, int n_in,
                              void* d_out, int out_size, void* d_ws, size_t ws_size,
                              hipStream_t stream) {
  const float* x1        = (const float*)d_in[0];
  const float* x2        = (const float*)d_in[1];
  const float* r_w1      = (const float*)d_in[2];
  const float* r_b1      = (const float*)d_in[3];
  const float* ln_g      = (const float*)d_in[4];
  const float* ln_b      = (const float*)d_in[5];
  const float* r_w2      = (const float*)d_in[6];
  const float* r_b2      = (const float*)d_in[7];
  const float* lf_b      = (const float*)d_in[9];
  const float* af2_b     = (const float*)d_in[11];
  const float* af3_b     = (const float*)d_in[13];
  const float* attn_in_b = (const float*)d_in[15];
  const float* attn_out_b= (const float*)d_in[17];
  float* out = (float*)d_out;

  // ws: mp[131072 f32] | w[128 f32] | zb | qo(=o) | kh | vt (each B*S*256 ush)
  //     | wb[524288 ush] | x2t[B*256*256 ush]  ~= 56.4 MB
  float* ws_mp = (float*)d_ws;
  float* ws_w  = ws_mp + 131072;
  ushort* ws_zb = (ushort*)(ws_w + 128);
  ushort* ws_qo = ws_zb + (size_t)B_*S_*256;
  ushort* ws_kh = ws_qo + (size_t)B_*S_*256;
  ushort* ws_vt = ws_kh + (size_t)B_*S_*256;
  ushort* ws_wb = ws_vt + (size_t)B_*S_*256;
  ushort* ws_xt = ws_wb + 524288;

  k_prep<<<dim3(768), 256, 0, stream>>>(x1, x2, (const float*)d_in[8], (const float*)d_in[10],
                                        (const float*)d_in[12], (const float*)d_in[14],
                                        (const float*)d_in[16], ws_zb, ws_wb, ws_xt, ws_mp);
  k_head<<<dim3(B_),   256, 0, stream>>>(ws_mp, r_w1, r_b1, ln_g, ln_b, r_w2, r_b2, ws_w);
  k_qkv <<<dim3(6,6,B_), 256, 0, stream>>>(ws_zb, ws_wb, attn_in_b, ws_qo, ws_kh, ws_vt);
  k_attn<<<dim3(2,8,B_), 256, 0, stream>>>(ws_qo, ws_kh, ws_vt, ws_qo);
  k_out <<<dim3(4,12,B_),256, 0, stream>>>(ws_zb, ws_wb, ws_qo, ws_xt,
                                           lf_b, af2_b, af3_b, attn_out_b, ws_w, out);
}

// Round 9
// 250.069 us; speedup vs baseline: 6.4668x; 1.0119x over previous
//
#include <hip/hip_runtime.h>
#include <hip/hip_bf16.h>
#include <math.h>

// Problem: SurMoE. B=32, N1=512, N2=256, D=256, H=8, HD=32, S=768.
// Outputs: gene (32,512,256) f32 then img (32,256,256) f32, concat flat.
#define B_ 32
#define N1_ 512
#define N2_ 256
#define D_ 256
#define S_ 768
#define IMG_OFF 4194304  // 32*512*256
#define QSCALE_ (0.17677669529663689f * 1.4426950408889634f)  // 1/sqrt(32) * log2(e)

typedef __attribute__((ext_vector_type(8))) short bf16x8;
typedef __attribute__((ext_vector_type(4))) float f32x4;
#define MFMA16(a, b, c) __builtin_amdgcn_mfma_f32_16x16x32_bf16(a, b, c, 0, 0, 0)

__device__ __forceinline__ ushort f2b(float f) {
  __hip_bfloat16 h = __float2bfloat16(f);
  return __builtin_bit_cast(ushort, h);
}
__device__ __forceinline__ uint pk2(float a, float b) {
  return (uint)f2b(a) | ((uint)f2b(b) << 16);
}
__device__ __forceinline__ float b2f(ushort u) {
  return __builtin_bit_cast(float, ((uint)u) << 16);
}
__device__ __forceinline__ float eluf(float v) { return v > 0.f ? v : expm1f(v); }

// async global->LDS, 16B per lane. g: per-lane global addr; l: WAVE-UNIFORM LDS base.
// HW scatters lane i to l + i*16 (m104/m108) -> LDS tiles must be unpadded.
__device__ __forceinline__ void gl16(const ushort* g, ushort* l) {
  __builtin_amdgcn_global_load_lds(
      (const __attribute__((address_space(1))) uint*)g,
      (__attribute__((address_space(3))) uint*)l, 16, 0, 0);
}

// ---------------- prep: z->bf16 staging + partial means + x2T (blocks 0..255) ----------------
// ---------------- + weights->bf16, Wq prescaled              (blocks 256..767) ----------------
// wb layout (elems): lf[0,64K) af2[64K,128K) af3[128K,256K) attn_in[256K,448K) attn_out[448K,512K)
__global__ __launch_bounds__(256) void k_prep(const float* __restrict__ x1,
                                              const float* __restrict__ x2,
                                              const float* __restrict__ lf_w,
                                              const float* __restrict__ af2_w,
                                              const float* __restrict__ af3_w,
                                              const float* __restrict__ attn_in_w,
                                              const float* __restrict__ attn_out_w,
                                              ushort* __restrict__ zb,
                                              ushort* __restrict__ wb,
                                              ushort* __restrict__ x2t,
                                              float* __restrict__ mp) {
  int t = threadIdx.x;
  if (blockIdx.x >= 256) {   // ---- weight conversion path ----
    int g = (blockIdx.x - 256)*256 + t;
    int e0 = g*4;
    const float* src; int loc; float sc = 1.f;
    if (e0 < 65536)       { src = lf_w;       loc = e0; }
    else if (e0 < 131072) { src = af2_w;      loc = e0 - 65536; }
    else if (e0 < 262144) { src = af3_w;      loc = e0 - 131072; }
    else if (e0 < 458752) { src = attn_in_w;  loc = e0 - 262144; if (loc < 65536) sc = QSCALE_; }
    else                  { src = attn_out_w; loc = e0 - 458752; }
    float4 v = *(const float4*)(src + loc);
    *(ushort4*)(wb + e0) = make_ushort4(f2b(v.x*sc), f2b(v.y*sc), f2b(v.z*sc), f2b(v.w*sc));
    return;
  }
  int b = blockIdx.x >> 3, s = blockIdx.x & 7;
  int c = t & 63;    // float4-column
  int rg = t >> 6;   // 0..3
  __shared__ float red[4][260];
  __shared__ ushort xt[32][266];
  float4 s1 = {0.f, 0.f, 0.f, 0.f};
  for (int i = 0; i < 16; ++i) {
    int r = s*64 + rg*16 + i;
    float4 v = *(const float4*)(x1 + ((size_t)(b*N1_) + r)*D_ + c*4);
    s1.x += v.x; s1.y += v.y; s1.z += v.z; s1.w += v.w;
    uint2 pk; pk.x = pk2(v.x, v.y); pk.y = pk2(v.z, v.w);
    *(uint2*)(zb + (size_t)b*196608 + (size_t)r*256 + c*4) = pk;
  }
  red[rg][c*4+0] = s1.x; red[rg][c*4+1] = s1.y; red[rg][c*4+2] = s1.z; red[rg][c*4+3] = s1.w;
  __syncthreads();
  {
    float v = red[0][t] + red[1][t] + red[2][t] + red[3][t];
    mp[(size_t)(b*8+s)*512 + t] = v * (1.0f/512.0f);
  }
  __syncthreads();
  float4 s2 = {0.f, 0.f, 0.f, 0.f};
  for (int i = 0; i < 8; ++i) {
    int rl = rg*8 + i;
    int r = s*32 + rl;
    float4 v = *(const float4*)(x2 + ((size_t)(b*N2_) + r)*D_ + c*4);
    s2.x += v.x; s2.y += v.y; s2.z += v.z; s2.w += v.w;
    ushort b0 = f2b(v.x), b1 = f2b(v.y), b2 = f2b(v.z), b3 = f2b(v.w);
    uint2 pk; pk.x = (uint)b0 | ((uint)b1 << 16); pk.y = (uint)b2 | ((uint)b3 << 16);
    *(uint2*)(zb + (size_t)b*196608 + (size_t)(512 + r)*256 + c*4) = pk;
    xt[rl][c*4+0] = b0; xt[rl][c*4+1] = b1; xt[rl][c*4+2] = b2; xt[rl][c*4+3] = b3;
  }
  red[rg][c*4+0] = s2.x; red[rg][c*4+1] = s2.y; red[rg][c*4+2] = s2.z; red[rg][c*4+3] = s2.w;
  __syncthreads();
  {
    float v = red[0][t] + red[1][t] + red[2][t] + red[3][t];
    mp[(size_t)(b*8+s)*512 + 256 + t] = v * (1.0f/256.0f);
  }
  // x2T: thread t owns d=t, writes n2 = s*32..s*32+31 (32 ushorts = 4 uint4)
  ushort* dst = x2t + (size_t)b*65536 + (size_t)t*256 + s*32;
  #pragma unroll
  for (int g = 0; g < 4; ++g) {
    uint4 w;
    w.x = (uint)xt[g*8+0][t] | ((uint)xt[g*8+1][t] << 16);
    w.y = (uint)xt[g*8+2][t] | ((uint)xt[g*8+3][t] << 16);
    w.z = (uint)xt[g*8+4][t] | ((uint)xt[g*8+5][t] << 16);
    w.w = (uint)xt[g*8+6][t] | ((uint)xt[g*8+7][t] << 16);
    *(uint4*)(dst + g*8) = w;
  }
}

// ---------------- router head ----------------
__global__ __launch_bounds__(256) void k_head(const float* __restrict__ mp, const float* __restrict__ r_w1,
                       const float* __restrict__ r_b1, const float* __restrict__ ln_g,
                       const float* __restrict__ ln_b, const float* __restrict__ r_w2,
                       const float* __restrict__ r_b2, float* __restrict__ wout) {
  int b = blockIdx.x;
  int j = threadIdx.x;  // 256
  __shared__ __align__(16) float ms[512];
  __shared__ float red[256];
  float a0 = 0.f, a1 = 0.f;
  for (int s = 0; s < 8; ++s) {
    a0 += mp[(size_t)(b*8+s)*512 + j];
    a1 += mp[(size_t)(b*8+s)*512 + 256 + j];
  }
  ms[j] = a0; ms[j+256] = a1;
  __syncthreads();
  float4 accv = {0.f, 0.f, 0.f, 0.f};
  const float4* wrow4 = (const float4*)(r_w1 + (size_t)j*512);
  const float4* ms4 = (const float4*)ms;
  for (int k = 0; k < 128; ++k) {
    float4 w = wrow4[k], m = ms4[k];
    accv.x += w.x*m.x; accv.y += w.y*m.y; accv.z += w.z*m.z; accv.w += w.w*m.w;
  }
  float acc = r_b1[j] + (accv.x + accv.y) + (accv.z + accv.w);
  red[j] = acc; __syncthreads();
  for (int off=128; off>0; off>>=1){ if (j<off) red[j]+=red[j+off]; __syncthreads(); }
  float mu = red[0] * (1.f/256.f); __syncthreads();
  float cd = acc - mu;
  red[j] = cd*cd; __syncthreads();
  for (int off=128; off>0; off>>=1){ if (j<off) red[j]+=red[j+off]; __syncthreads(); }
  float var = red[0]*(1.f/256.f); __syncthreads();
  float xn = cd * rsqrtf(var + 1e-5f) * ln_g[j] + ln_b[j];
  float h = 0.5f*xn*(1.f+erff(xn*0.70710678118654752f));
  float lg[4];
  for (int e=0;e<4;++e){
    red[j] = h * r_w2[e*256 + j]; __syncthreads();
    for (int off=128; off>0; off>>=1){ if (j<off) red[j]+=red[j+off]; __syncthreads(); }
    lg[e] = red[0] + r_b2[e]; __syncthreads();
  }
  if (j==0){
    float mx = fmaxf(fmaxf(lg[0],lg[1]),fmaxf(lg[2],lg[3]));
    float e0=expf(lg[0]-mx),e1=expf(lg[1]-mx),e2=expf(lg[2]-mx),e3=expf(lg[3]-mx);
    float s=e0+e1+e2+e3;
    wout[b*4+0]=e0/s; wout[b*4+1]=e1/s; wout[b*4+2]=e2/s; wout[b*4+3]=e3/s;
  }
}

// ---------------- qkv (128x128 tiles, async staging): q->qo (prescaled), k->kh, v->vT ----------------
__global__ __launch_bounds__(256) void k_qkv(const ushort* __restrict__ zb, const ushort* __restrict__ wb,
                      const float* __restrict__ bias,
                      ushort* __restrict__ qo, ushort* __restrict__ kh,
                      ushort* __restrict__ vt) {
  int ct = blockIdx.x, nt = blockIdx.y, b = blockIdx.z;
  int tid = threadIdx.x;
  int lane = tid & 63, wid = tid >> 6;
  int wm = wid >> 1, wn = wid & 1;
  int l15 = lane & 15, quad = lane >> 4;
  __shared__ __align__(16) ushort As[128][64];
  __shared__ __align__(16) ushort Ws[128][64];
  f32x4 acc[4][4] = {};
  int n0 = nt*128, c0 = ct*128;
  // async-staging mapping: wave wid covers rows wid*32 + j*8 + (lane>>3), col (lane&7)*8
  const ushort* g_a = zb + (size_t)b*196608 + (size_t)(n0 + wid*32 + (lane>>3))*256 + (lane&7)*8;
  const ushort* g_w = wb + 262144 + (size_t)(c0 + wid*32 + (lane>>3))*256 + (lane&7)*8;
  for (int k0 = 0; k0 < 256; k0 += 64) {
    #pragma unroll
    for (int j = 0; j < 4; ++j) {
      gl16(g_a + (size_t)j*8*256 + k0, &As[wid*32 + j*8][0]);
      gl16(g_w + (size_t)j*8*256 + k0, &Ws[wid*32 + j*8][0]);
    }
    __syncthreads();
    #pragma unroll
    for (int kc = 0; kc < 2; ++kc) {
      bf16x8 af[4], bfr[4];
      #pragma unroll
      for (int im = 0; im < 4; ++im) af[im] = *(bf16x8*)&As[wm*64 + im*16 + l15][kc*32 + quad*8];
      #pragma unroll
      for (int in = 0; in < 4; ++in) bfr[in] = *(bf16x8*)&Ws[wn*64 + in*16 + l15][kc*32 + quad*8];
      #pragma unroll
      for (int im = 0; im < 4; ++im)
        #pragma unroll
        for (int in = 0; in < 4; ++in)
          acc[im][in] = MFMA16(af[im], bfr[in], acc[im][in]);
    }
    __syncthreads();
  }
  if (ct < 2) {          // q: prescaled, [b][n][256]
    #pragma unroll
    for (int im = 0; im < 4; ++im)
      #pragma unroll
      for (int reg = 0; reg < 4; ++reg) {
        int n = n0 + wm*64 + im*16 + quad*4 + reg;
        #pragma unroll
        for (int in = 0; in < 4; ++in) {
          int c = c0 + wn*64 + in*16 + l15;
          qo[((size_t)(b*S_)+n)*256 + c] = f2b(acc[im][in][reg] + bias[c]*QSCALE_);
        }
      }
  } else if (ct < 4) {   // k: kh[b][h][n][32]
    #pragma unroll
    for (int im = 0; im < 4; ++im)
      #pragma unroll
      for (int reg = 0; reg < 4; ++reg) {
        int n = n0 + wm*64 + im*16 + quad*4 + reg;
        #pragma unroll
        for (int in = 0; in < 4; ++in) {
          int c = c0 + wn*64 + in*16 + l15;        // global col in [256,512)
          int kc2 = c - 256; int h = kc2 >> 5, d = kc2 & 31;
          kh[(((size_t)(b*8+h))*S_ + n)*32 + d] = f2b(acc[im][in][reg] + bias[c]);
        }
      }
  } else {               // v: vT[b][h][32][768]
    #pragma unroll
    for (int im = 0; im < 4; ++im) {
      int nb = n0 + wm*64 + im*16 + quad*4;
      #pragma unroll
      for (int in = 0; in < 4; ++in) {
        int c = c0 + wn*64 + in*16 + l15;          // [512,768)
        float bs = bias[c];
        int vcol = c - 512; int h = vcol >> 5, d = vcol & 31;
        uint2 pk;
        pk.x = pk2(acc[im][in][0] + bs, acc[im][in][1] + bs);
        pk.y = pk2(acc[im][in][2] + bs, acc[im][in][3] + bs);
        *(uint2*)&vt[(((size_t)(b*8+h))*32 + d)*S_ + nb] = pk;
      }
    }
  }
}

// ---------------- flash attention, no-max softmax, 384 q/block, async K/V staging ----------------
// o aliases qo: block (qh,h,b) reads exactly the q-slice it overwrites.
__global__ __launch_bounds__(256) void k_attn(const ushort* __restrict__ qo,
                                              const ushort* __restrict__ kh,
                                              const ushort* __restrict__ vt,
                                              ushort* __restrict__ obuf) {
  int qhf = blockIdx.x, h = blockIdx.y, b = blockIdx.z;
  int tid = threadIdx.x;
  int lane = tid & 63, w = tid >> 6;
  int l15 = lane & 15, quad = lane >> 4;
  __shared__ __align__(16) ushort Ks[64][32];
  __shared__ __align__(16) ushort Vts[32][64];
  __shared__ __align__(16) ushort Ps[4][16][72];

  int qbase = qhf*384 + w*96;
  bf16x8 bq[6];
  #pragma unroll
  for (int u = 0; u < 6; ++u)
    bq[u] = *(const bf16x8*)(qo + ((size_t)(b*S_) + qbase + u*16 + l15)*256 + h*32 + quad*8);

  f32x4 ao[6][2] = {};
  float lacc[6] = {};

  const ushort* khb = kh + ((size_t)(b*8+h))*S_*32;
  const ushort* vtb = vt + ((size_t)(b*8+h))*32*S_;
  // async staging per-lane global bases (wave w: Ks rows w*16+.., Vts rows w*8+..)
  const ushort* g_k = khb + (size_t)(w*16 + (lane>>2))*32 + (lane&3)*8;
  const ushort* g_v = vtb + (size_t)(w*8 + (lane>>3))*S_ + (lane&7)*8;

  for (int kt = 0; kt < 12; ++kt) {
    __syncthreads();
    gl16(g_k + (size_t)(kt*64)*32, &Ks[w*16][0]);
    gl16(g_v + kt*64, &Vts[w*8][0]);
    __syncthreads();

    bf16x8 ak[4];
    #pragma unroll
    for (int t = 0; t < 4; ++t) ak[t] = *(bf16x8*)&Ks[t*16 + l15][quad*8];
    bf16x8 av[2][2];
    #pragma unroll
    for (int im = 0; im < 2; ++im)
      #pragma unroll
      for (int kc = 0; kc < 2; ++kc)
        av[im][kc] = *(bf16x8*)&Vts[im*16 + l15][kc*32 + quad*8];

    #pragma unroll
    for (int u = 0; u < 6; ++u) {
      f32x4 sf[4];
      #pragma unroll
      for (int t = 0; t < 4; ++t) {
        f32x4 z = {0.f, 0.f, 0.f, 0.f};
        sf[t] = MFMA16(ak[t], bq[u], z);   // S^T·log2e (scale folded into q)
      }
      #pragma unroll
      for (int t = 0; t < 4; ++t) {
        float p0 = __builtin_amdgcn_exp2f(sf[t][0]);
        float p1 = __builtin_amdgcn_exp2f(sf[t][1]);
        float p2 = __builtin_amdgcn_exp2f(sf[t][2]);
        float p3 = __builtin_amdgcn_exp2f(sf[t][3]);
        lacc[u] += (p0 + p1) + (p2 + p3);
        uint2 pk;
        pk.x = pk2(p0, p1);
        pk.y = pk2(p2, p3);
        *(uint2*)&Ps[w][l15][t*16 + quad*4] = pk;
      }
      #pragma unroll
      for (int kc = 0; kc < 2; ++kc) {
        bf16x8 bp = *(bf16x8*)&Ps[w][l15][kc*32 + quad*8];
        ao[u][0] = MFMA16(av[0][kc], bp, ao[u][0]);
        ao[u][1] = MFMA16(av[1][kc], bp, ao[u][1]);
      }
    }
  }
  #pragma unroll
  for (int u = 0; u < 6; ++u) {
    float l = lacc[u];
    l += __shfl_xor(l, 16, 64);
    l += __shfl_xor(l, 32, 64);
    float linv = 1.f / l;
    int n = qbase + u*16 + l15;
    ushort* orow = obuf + ((size_t)(b*S_)+n)*256 + h*32;
    #pragma unroll
    for (int im = 0; im < 2; ++im) {
      uint2 pk;
      pk.x = pk2(ao[u][im][0]*linv, ao[u][im][1]*linv);
      pk.y = pk2(ao[u][im][2]*linv, ao[u][im][3]*linv);
      *(uint2*)(orow + im*16 + quad*4) = pk;
    }
  }
}

// ---------------- fused output: out = w0*elu(lf) + w1*(elu(a1)+elu(a2)) + w2*proj + w3*z ----------------
// Single fused k-loop, K=32 chunks, async global_load_lds staging, 32KB LDS -> 5 blocks/CU.
__global__ __launch_bounds__(256) void k_out(const ushort* __restrict__ zb, const ushort* __restrict__ wb,
                      const ushort* __restrict__ ob, const ushort* __restrict__ x2t,
                      const float* __restrict__ lf_b, const float* __restrict__ af2_b,
                      const float* __restrict__ af3_b, const float* __restrict__ ao_b,
                      const float* __restrict__ wgt, float* __restrict__ out) {
  int dt = blockIdx.x, nt = blockIdx.y, b = blockIdx.z;
  int tid = threadIdx.x;
  int lane = tid & 63, wid = tid >> 6;
  int wm = wid >> 1, wn = wid & 1;
  int l15 = lane & 15, quad = lane >> 4;
  __shared__ __align__(16) ushort A1[64][32];
  __shared__ __align__(16) ushort A2[64][32];
  __shared__ __align__(16) ushort A3[64][32];
  __shared__ __align__(16) ushort A4[64][32];
  __shared__ __align__(16) ushort W1s[64][32];
  __shared__ __align__(16) ushort W2s[64][32];
  __shared__ __align__(16) ushort W3s[64][32];
  __shared__ __align__(16) ushort W4s[64][32];
  f32x4 a_lf[2][2] = {}, a_a1[2][2] = {}, a_a2[2][2] = {}, a_pj[2][2] = {};
  int n0 = nt*64, d0 = dt*64;
  int xr0 = ((nt < 8) ? nt : (nt - 8)) * 64;   // xout row base (x1/af3 rows)
  int sr = tid >> 2, sc4 = (tid & 3) * 8;      // per-lane global mapping == lane*16B LDS scatter

  const ushort* p_a1 = zb + (size_t)b*196608 + (size_t)(n0+sr)*256 + sc4;   // z rows
  const ushort* p_a2 = zb + (size_t)b*196608 + (size_t)(xr0+sr)*256 + sc4;  // x1 rows
  const ushort* p_a3 = wb + 131072 + (size_t)(xr0+sr)*256 + sc4;            // af3 rows
  const ushort* p_a4 = ob + ((size_t)(b*S_) + n0 + sr)*256 + sc4;           // o rows
  const ushort* p_w1 = wb + (size_t)(d0+sr)*256 + sc4;                      // lf_w
  const ushort* p_w2 = wb + 65536 + (size_t)(d0+sr)*256 + sc4;              // af2_w
  const ushort* p_w3 = x2t + (size_t)b*65536 + (size_t)(d0+sr)*256 + sc4;   // x2^T rows (d)
  const ushort* p_w4 = wb + 458752 + (size_t)(d0+sr)*256 + sc4;             // attn_out_w
  ushort* l_a1 = &A1[wid*16][0];
  ushort* l_a2 = &A2[wid*16][0];
  ushort* l_a3 = &A3[wid*16][0];
  ushort* l_a4 = &A4[wid*16][0];
  ushort* l_w1 = &W1s[wid*16][0];
  ushort* l_w2 = &W2s[wid*16][0];
  ushort* l_w3 = &W3s[wid*16][0];
  ushort* l_w4 = &W4s[wid*16][0];

  for (int k0 = 0; k0 < 256; k0 += 32) {
    gl16(p_a1 + k0, l_a1);
    gl16(p_a2 + k0, l_a2);
    gl16(p_a3 + k0, l_a3);
    gl16(p_a4 + k0, l_a4);
    gl16(p_w1 + k0, l_w1);
    gl16(p_w2 + k0, l_w2);
    gl16(p_w3 + k0, l_w3);
    gl16(p_w4 + k0, l_w4);
    __syncthreads();
    {
      int ko = quad*8;
      bf16x8 x0, x1r, y0, y1;
      x0 = *(bf16x8*)&A1[wm*32 + l15][ko];  x1r = *(bf16x8*)&A1[wm*32 + 16 + l15][ko];
      y0 = *(bf16x8*)&W1s[wn*32 + l15][ko]; y1  = *(bf16x8*)&W1s[wn*32 + 16 + l15][ko];
      a_lf[0][0] = MFMA16(x0, y0, a_lf[0][0]);  a_lf[0][1] = MFMA16(x0, y1, a_lf[0][1]);
      a_lf[1][0] = MFMA16(x1r, y0, a_lf[1][0]); a_lf[1][1] = MFMA16(x1r, y1, a_lf[1][1]);
      x0 = *(bf16x8*)&A2[wm*32 + l15][ko];  x1r = *(bf16x8*)&A2[wm*32 + 16 + l15][ko];
      y0 = *(bf16x8*)&W2s[wn*32 + l15][ko]; y1  = *(bf16x8*)&W2s[wn*32 + 16 + l15][ko];
      a_a1[0][0] = MFMA16(x0, y0, a_a1[0][0]);  a_a1[0][1] = MFMA16(x0, y1, a_a1[0][1]);
      a_a1[1][0] = MFMA16(x1r, y0, a_a1[1][0]); a_a1[1][1] = MFMA16(x1r, y1, a_a1[1][1]);
      x0 = *(bf16x8*)&A3[wm*32 + l15][ko];  x1r = *(bf16x8*)&A3[wm*32 + 16 + l15][ko];
      y0 = *(bf16x8*)&W3s[wn*32 + l15][ko]; y1  = *(bf16x8*)&W3s[wn*32 + 16 + l15][ko];
      a_a2[0][0] = MFMA16(x0, y0, a_a2[0][0]);  a_a2[0][1] = MFMA16(x0, y1, a_a2[0][1]);
      a_a2[1][0] = MFMA16(x1r, y0, a_a2[1][0]); a_a2[1][1] = MFMA16(x1r, y1, a_a2[1][1]);
      x0 = *(bf16x8*)&A4[wm*32 + l15][ko];  x1r = *(bf16x8*)&A4[wm*32 + 16 + l15][ko];
      y0 = *(bf16x8*)&W4s[wn*32 + l15][ko]; y1  = *(bf16x8*)&W4s[wn*32 + 16 + l15][ko];
      a_pj[0][0] = MFMA16(x0, y0, a_pj[0][0]);  a_pj[0][1] = MFMA16(x0, y1, a_pj[0][1]);
      a_pj[1][0] = MFMA16(x1r, y0, a_pj[1][0]); a_pj[1][1] = MFMA16(x1r, y1, a_pj[1][1]);
    }
    __syncthreads();
  }
  // ---- epilogue (z-term from bf16 zb; rows L2-hot from A1 staging) ----
  float w0 = wgt[b*4+0], w1v = wgt[b*4+1], w2v = wgt[b*4+2], w3 = wgt[b*4+3];
  #pragma unroll
  for (int im = 0; im < 2; ++im) {
    #pragma unroll
    for (int reg = 0; reg < 4; ++reg) {
      int rl = wm*32 + im*16 + quad*4 + reg;   // local row
      int n = n0 + rl;
      int rx = xr0 + rl;                        // xout row (x1/af3 index)
      const ushort* zr = zb + (size_t)b*196608 + (size_t)n*256;
      float* orw = (nt < 8) ? out + ((size_t)(b*N1_) + n)*D_
                            : out + (size_t)IMG_OFF + ((size_t)(b*N2_) + (n - 512))*D_;
      float b3 = af3_b[rx];
      #pragma unroll
      for (int in = 0; in < 2; ++in) {
        int d = d0 + wn*32 + in*16 + l15;
        float v = w0*eluf(a_lf[im][in][reg] + lf_b[d])
                + w1v*(eluf(a_a1[im][in][reg] + af2_b[d]) + eluf(a_a2[im][in][reg] + b3))
                + w2v*(a_pj[im][in][reg] + ao_b[d])
                + w3*b2f(zr[d]);
        orw[d] = v;
      }
    }
  }
}

extern "C" void kernel_launch(void* const* d_in, const int* in_sizes, int n_in,
                              void* d_out, int out_size, void* d_ws, size_t ws_size,
                              hipStream_t stream) {
  const float* x1        = (const float*)d_in[0];
  const float* x2        = (const float*)d_in[1];
  const float* r_w1      = (const float*)d_in[2];
  const float* r_b1      = (const float*)d_in[3];
  const float* ln_g      = (const float*)d_in[4];
  const float* ln_b      = (const float*)d_in[5];
  const float* r_w2      = (const float*)d_in[6];
  const float* r_b2      = (const float*)d_in[7];
  const float* lf_b      = (const float*)d_in[9];
  const float* af2_b     = (const float*)d_in[11];
  const float* af3_b     = (const float*)d_in[13];
  const float* attn_in_b = (const float*)d_in[15];
  const float* attn_out_b= (const float*)d_in[17];
  float* out = (float*)d_out;

  // ws: mp[131072 f32] | w[128 f32] | zb | qo(=o) | kh | vt (each B*S*256 ush)
  //     | wb[524288 ush] | x2t[B*256*256 ush]  ~= 56.4 MB
  float* ws_mp = (float*)d_ws;
  float* ws_w  = ws_mp + 131072;
  ushort* ws_zb = (ushort*)(ws_w + 128);
  ushort* ws_qo = ws_zb + (size_t)B_*S_*256;
  ushort* ws_kh = ws_qo + (size_t)B_*S_*256;
  ushort* ws_vt = ws_kh + (size_t)B_*S_*256;
  ushort* ws_wb = ws_vt + (size_t)B_*S_*256;
  ushort* ws_xt = ws_wb + 524288;

  k_prep<<<dim3(768), 256, 0, stream>>>(x1, x2, (const float*)d_in[8], (const float*)d_in[10],
                                        (const float*)d_in[12], (const float*)d_in[14],
                                        (const float*)d_in[16], ws_zb, ws_wb, ws_xt, ws_mp);
  k_head<<<dim3(B_),   256, 0, stream>>>(ws_mp, r_w1, r_b1, ln_g, ln_b, r_w2, r_b2, ws_w);
  k_qkv <<<dim3(6,6,B_), 256, 0, stream>>>(ws_zb, ws_wb, attn_in_b, ws_qo, ws_kh, ws_vt);
  k_attn<<<dim3(2,8,B_), 256, 0, stream>>>(ws_qo, ws_kh, ws_vt, ws_qo);
  k_out <<<dim3(4,12,B_),256, 0, stream>>>(ws_zb, ws_wb, ws_qo, ws_xt,
                                           lf_b, af2_b, af3_b, attn_out_b, ws_w, out);
}